// Round 1
// baseline (15059.375 us; speedup 1.0000x reference)
//
#include <hip/hip_runtime.h>
#include <cstdint>
#include <cstddef>

// ---------------------------------------------------------------------------
// HamiltonianFlowModel: flow_fwd -> RK4(grad_H @ M^T) -> flow_inv
// fp32 baseline; bf16 only for 256-wide LDS intermediates inside rk4.
// ---------------------------------------------------------------------------

namespace {
constexpr int kDim = 64;   // DIM
constexpr int kQd  = 32;   // DIM/2
constexpr int kNl  = 6;    // NLAYERS
constexpr int kHf  = 128;  // HF
constexpr int kHh  = 256;  // HH
constexpr float kDt = 0.05f;
}

// ---------------- helpers ----------------
__device__ __forceinline__ uint32_t f2bf(float f) {
  uint32_t u = __float_as_uint(f);
  return (u + 0x7fffu + ((u >> 16) & 1u)) >> 16;   // RNE bf16
}
__device__ __forceinline__ uint32_t pkbf(float a, float b) {
  return f2bf(a) | (f2bf(b) << 16);
}
__device__ __forceinline__ void upk8(uint4 v, float* __restrict__ f) {
  f[0] = __uint_as_float(v.x << 16); f[1] = __uint_as_float(v.x & 0xffff0000u);
  f[2] = __uint_as_float(v.y << 16); f[3] = __uint_as_float(v.y & 0xffff0000u);
  f[4] = __uint_as_float(v.z << 16); f[5] = __uint_as_float(v.z & 0xffff0000u);
  f[6] = __uint_as_float(v.w << 16); f[7] = __uint_as_float(v.w & 0xffff0000u);
}
__device__ __forceinline__ void ld8(const float* __restrict__ p, float* __restrict__ f) {
  const float4* q = reinterpret_cast<const float4*>(p);
  float4 a = q[0], b = q[1];
  f[0]=a.x; f[1]=a.y; f[2]=a.z; f[3]=a.w; f[4]=b.x; f[5]=b.y; f[6]=b.z; f[7]=b.w;
}

// ---------------- prep: M = (A - A^T) - L L^T ----------------
__global__ void prep_M(const float* __restrict__ A, const float* __restrict__ Lp,
                       float* __restrict__ M) {
  int n = blockIdx.x * 256 + threadIdx.x;
  if (n >= kDim * kDim) return;
  int d = n >> 6, e = n & 63;
  int kmax = min(d, e);
  float sum = 0.f;
  for (int k = 0; k <= kmax; ++k) {
    float ld = (k < d) ? Lp[d * kDim + k] : log1pf(expf(Lp[d * kDim + d]));
    float le = (k < e) ? Lp[e * kDim + k] : log1pf(expf(Lp[e * kDim + e]));
    sum += ld * le;
  }
  M[n] = A[d * kDim + e] - A[e * kDim + d] - sum;
}

// ---------------- prep: transpose flow W2 [6][32][128] -> [6][128][32] ----------------
__global__ void prep_tr(const float* __restrict__ sW2, const float* __restrict__ tW2,
                        float* __restrict__ sW2T, float* __restrict__ tW2T) {
  int n = blockIdx.x * 256 + threadIdx.x;
  if (n >= kNl * kHf * kQd) return;
  int l = n / (kHf * kQd);
  int r = n % (kHf * kQd);
  int j = r / kQd;
  int k = r % kQd;
  sW2T[n] = sW2[l * kQd * kHf + k * kHf + j];
  tW2T[n] = tW2[l * kQd * kHf + k * kHf + j];
}

// ---------------- flow (fwd/inv), thread-per-sample ----------------
template <bool FWD>
__global__ __launch_bounds__(256, 2)
void flow_kernel(const float* __restrict__ io_in, float* __restrict__ io_out,
                 const float* __restrict__ W1s, const float* __restrict__ b1s,
                 const float* __restrict__ W2Ts, const float* __restrict__ b2s,
                 const float* __restrict__ W1t, const float* __restrict__ b1t,
                 const float* __restrict__ W2Tt, const float* __restrict__ b2t) {
  const size_t s = (size_t)blockIdx.x * blockDim.x + threadIdx.x;
  float x[kDim];
  {
    const float4* p = reinterpret_cast<const float4*>(io_in + s * kDim);
#pragma unroll
    for (int i = 0; i < kDim / 4; ++i) {
      float4 v = p[i];
      x[4*i+0] = v.x; x[4*i+1] = v.y; x[4*i+2] = v.z; x[4*i+3] = v.w;
    }
  }

#define FLOW_LAYER(CB, TB)                                                           \
  do {                                                                               \
    float aS[kQd], aT[kQd];                                                          \
    _Pragma("unroll")                                                                \
    for (int k = 0; k < kQd; ++k) {                                                  \
      aS[k] = b2s[l * kQd + k];                                                      \
      aT[k] = b2t[l * kQd + k];                                                      \
    }                                                                                \
    for (int j = 0; j < kHf; ++j) {                                                  \
      float hs = b1s[l * kHf + j];                                                   \
      float ht = b1t[l * kHf + j];                                                   \
      const float4* w1sp = reinterpret_cast<const float4*>(W1s + ((size_t)l*kHf + j)*kQd); \
      const float4* w1tp = reinterpret_cast<const float4*>(W1t + ((size_t)l*kHf + j)*kQd); \
      _Pragma("unroll")                                                              \
      for (int kk = 0; kk < kQd / 4; ++kk) {                                         \
        float4 ws = w1sp[kk], wt = w1tp[kk];                                         \
        hs += ws.x*x[CB+4*kk+0] + ws.y*x[CB+4*kk+1] + ws.z*x[CB+4*kk+2] + ws.w*x[CB+4*kk+3]; \
        ht += wt.x*x[CB+4*kk+0] + wt.y*x[CB+4*kk+1] + wt.z*x[CB+4*kk+2] + wt.w*x[CB+4*kk+3]; \
      }                                                                              \
      hs = fmaxf(hs, 0.0f); ht = fmaxf(ht, 0.0f);                                    \
      const float4* w2sp = reinterpret_cast<const float4*>(W2Ts + ((size_t)l*kHf + j)*kQd); \
      const float4* w2tp = reinterpret_cast<const float4*>(W2Tt + ((size_t)l*kHf + j)*kQd); \
      _Pragma("unroll")                                                              \
      for (int kk = 0; kk < kQd / 4; ++kk) {                                         \
        float4 vs = w2sp[kk], vt = w2tp[kk];                                         \
        aS[4*kk+0] += vs.x*hs; aS[4*kk+1] += vs.y*hs;                                \
        aS[4*kk+2] += vs.z*hs; aS[4*kk+3] += vs.w*hs;                                \
        aT[4*kk+0] += vt.x*ht; aT[4*kk+1] += vt.y*ht;                                \
        aT[4*kk+2] += vt.z*ht; aT[4*kk+3] += vt.w*ht;                                \
      }                                                                              \
    }                                                                                \
    _Pragma("unroll")                                                                \
    for (int k = 0; k < kQd; ++k) {                                                  \
      float sv = tanhf(aS[k]);                                                       \
      float tv = aT[k];                                                              \
      if (FWD) x[TB + k] = x[TB + k] * __expf(sv) + tv;                              \
      else     x[TB + k] = (x[TB + k] - tv) * __expf(-sv);                           \
    }                                                                                \
  } while (0)

#pragma unroll 1
  for (int li = 0; li < kNl; ++li) {
    const int l = FWD ? li : (kNl - 1 - li);
    if ((l & 1) == 0) { FLOW_LAYER(0, kQd); }
    else              { FLOW_LAYER(kQd, 0); }
  }
#undef FLOW_LAYER

  {
    float4* p = reinterpret_cast<float4*>(io_out + s * kDim);
#pragma unroll
    for (int i = 0; i < kDim / 4; ++i) {
      p[i] = make_float4(x[4*i+0], x[4*i+1], x[4*i+2], x[4*i+3]);
    }
  }
}

// ---------------- RK4 Hamiltonian dynamics ----------------
// Block: 256 threads, 32 samples. Mapping A: sg=tid>>5 (4 samples each),
// jg=tid&31 (8 units each). Mapping B: sB=tid>>3 (1 sample), dg=tid&7 (8 dims).

// mid_fwd: a = X(bf16 LDS) @ W^T + b;  out = sigmoid(a)*w3row  (bf16)
__device__ __forceinline__ void mid_fwd(const float* __restrict__ W,
                                        const float* __restrict__ b,
                                        const float* __restrict__ w3p,
                                        const unsigned short (*__restrict__ xin)[kHh],
                                        unsigned short (*__restrict__ gout)[kHh],
                                        int sg, int jg) {
  float bias[8], w3[8];
  ld8(b + jg * 8, bias);
  ld8(w3p + jg * 8, w3);
  float acc[4][8];
#pragma unroll
  for (int i = 0; i < 4; ++i)
#pragma unroll
    for (int jj = 0; jj < 8; ++jj) acc[i][jj] = bias[jj];
#pragma unroll 2
  for (int k = 0; k < kHh; k += 8) {
    float xv[4][8];
#pragma unroll
    for (int i = 0; i < 4; ++i)
      upk8(*reinterpret_cast<const uint4*>(&xin[sg*4+i][k]), xv[i]);
#pragma unroll
    for (int jj = 0; jj < 8; ++jj) {
      const float4* wr = reinterpret_cast<const float4*>(&W[(size_t)(jg*8+jj)*kHh + k]);
      float4 w0 = wr[0], w1 = wr[1];
#pragma unroll
      for (int i = 0; i < 4; ++i) {
        acc[i][jj] += w0.x*xv[i][0] + w0.y*xv[i][1] + w0.z*xv[i][2] + w0.w*xv[i][3]
                    + w1.x*xv[i][4] + w1.y*xv[i][5] + w1.z*xv[i][6] + w1.w*xv[i][7];
      }
    }
  }
#pragma unroll
  for (int i = 0; i < 4; ++i) {
    float gv[8];
#pragma unroll
    for (int jj = 0; jj < 8; ++jj) {
      float sig = 1.0f / (1.0f + __expf(-acc[i][jj]));
      gv[jj] = sig * w3[jj];
    }
    *reinterpret_cast<uint4*>(&gout[sg*4+i][jg*8]) =
        make_uint4(pkbf(gv[0],gv[1]), pkbf(gv[2],gv[3]), pkbf(gv[4],gv[5]), pkbf(gv[6],gv[7]));
  }
}

// mid_bwd: gh = (G @ W) * sig  -> hout(bf16).  Reduction over rows of W.
__device__ __forceinline__ void mid_bwd(const float* __restrict__ W,
                                        const unsigned short (*__restrict__ gin)[kHh],
                                        const unsigned short (*__restrict__ sigin)[kHh],
                                        unsigned short (*__restrict__ hout)[kHh],
                                        int sg, int jg) {
  const int k0 = jg * 8;
  float acc[4][8];
#pragma unroll
  for (int i = 0; i < 4; ++i)
#pragma unroll
    for (int kk = 0; kk < 8; ++kk) acc[i][kk] = 0.f;
#pragma unroll 2
  for (int j = 0; j < kHh; j += 8) {
    float gx[4][8];
#pragma unroll
    for (int i = 0; i < 4; ++i)
      upk8(*reinterpret_cast<const uint4*>(&gin[sg*4+i][j]), gx[i]);
#pragma unroll
    for (int jj = 0; jj < 8; ++jj) {
      const float4* wr = reinterpret_cast<const float4*>(&W[(size_t)(j+jj)*kHh + k0]);
      float4 w0 = wr[0], w1 = wr[1];
#pragma unroll
      for (int i = 0; i < 4; ++i) {
        float gval = gx[i][jj];
        acc[i][0] += gval*w0.x; acc[i][1] += gval*w0.y;
        acc[i][2] += gval*w0.z; acc[i][3] += gval*w0.w;
        acc[i][4] += gval*w1.x; acc[i][5] += gval*w1.y;
        acc[i][6] += gval*w1.z; acc[i][7] += gval*w1.w;
      }
    }
  }
#pragma unroll
  for (int i = 0; i < 4; ++i) {
    float sv[8];
    upk8(*reinterpret_cast<const uint4*>(&sigin[sg*4+i][k0]), sv);
    float r[8];
#pragma unroll
    for (int kk = 0; kk < 8; ++kk) r[kk] = acc[i][kk] * sv[kk];
    *reinterpret_cast<uint4*>(&hout[sg*4+i][k0]) =
        make_uint4(pkbf(r[0],r[1]), pkbf(r[2],r[3]), pkbf(r[4],r[5]), pkbf(r[6],r[7]));
  }
}

// in_fwd: a = Z(f32 LDS, first K cols) @ W^T + b; h=softplus(a), s=sigmoid(a)
template <int K>
__device__ __forceinline__ void in_fwd(const float* __restrict__ W,
                                       const float* __restrict__ b,
                                       const float (*__restrict__ zin)[kDim],
                                       unsigned short (*__restrict__ hout)[kHh],
                                       unsigned short (*__restrict__ sout)[kHh],
                                       int sg, int jg) {
  float bias[8];
  ld8(b + jg * 8, bias);
  float acc[4][8];
#pragma unroll
  for (int i = 0; i < 4; ++i)
#pragma unroll
    for (int jj = 0; jj < 8; ++jj) acc[i][jj] = bias[jj];
#pragma unroll 2
  for (int k = 0; k < K; k += 4) {
    float4 xv[4];
#pragma unroll
    for (int i = 0; i < 4; ++i)
      xv[i] = *reinterpret_cast<const float4*>(&zin[sg*4+i][k]);
#pragma unroll
    for (int jj = 0; jj < 8; ++jj) {
      float4 w = *reinterpret_cast<const float4*>(&W[(size_t)(jg*8+jj)*K + k]);
#pragma unroll
      for (int i = 0; i < 4; ++i)
        acc[i][jj] += w.x*xv[i].x + w.y*xv[i].y + w.z*xv[i].z + w.w*xv[i].w;
    }
  }
#pragma unroll
  for (int i = 0; i < 4; ++i) {
    float sp[8], sgm[8];
#pragma unroll
    for (int jj = 0; jj < 8; ++jj) {
      float a = acc[i][jj];
      float e = __expf(a);
      float d1 = 1.0f + e;
      sp[jj]  = __logf(d1);
      sgm[jj] = e / d1;
    }
    *reinterpret_cast<uint4*>(&hout[sg*4+i][jg*8]) =
        make_uint4(pkbf(sp[0],sp[1]), pkbf(sp[2],sp[3]), pkbf(sp[4],sp[5]), pkbf(sp[6],sp[7]));
    *reinterpret_cast<uint4*>(&sout[sg*4+i][jg*8]) =
        make_uint4(pkbf(sgm[0],sgm[1]), pkbf(sgm[2],sgm[3]), pkbf(sgm[4],sgm[5]), pkbf(sgm[6],sgm[7]));
  }
}

__global__ __launch_bounds__(256, 2)
void rk4_kernel(float* __restrict__ qp, const float* __restrict__ u,
                const float* __restrict__ kW1, const float* __restrict__ kb1,
                const float* __restrict__ kW2, const float* __restrict__ kb2,
                const float* __restrict__ kW3,
                const float* __restrict__ vW1, const float* __restrict__ vb1,
                const float* __restrict__ vW2, const float* __restrict__ vb2,
                const float* __restrict__ vW3,
                const float* __restrict__ Bc, const float* __restrict__ M) {
  __shared__ __align__(16) float zsh[32][kDim];
  __shared__ __align__(16) float gH[32][kDim];
  __shared__ __align__(16) unsigned short h1[32][kHh];
  __shared__ __align__(16) unsigned short s1[32][kHh];
  __shared__ __align__(16) unsigned short g2[32][kHh];

  const int tid = threadIdx.x;
  const int sg = tid >> 5;
  const int jg = tid & 31;
  const int sB = tid >> 3;
  const int dg = tid & 7;
  const int d0 = dg * 8;
  const size_t base = (size_t)blockIdx.x * 32;

  float qp0[8], accRK[8], bc8[8];
  {
    const float4* p = reinterpret_cast<const float4*>(qp + (base + sB) * kDim + d0);
    float4 a = p[0], b = p[1];
    qp0[0]=a.x; qp0[1]=a.y; qp0[2]=a.z; qp0[3]=a.w;
    qp0[4]=b.x; qp0[5]=b.y; qp0[6]=b.z; qp0[7]=b.w;
  }
  const float u_s = u[base + sB];
#pragma unroll
  for (int i = 0; i < 8; ++i) {
    int d = d0 + i;
    bc8[i] = (d >= kQd) ? Bc[d - kQd] : 0.0f;   // Bc is [QD][1]
    accRK[i] = 0.0f;
  }
  {
    float4* zp = reinterpret_cast<float4*>(&zsh[sB][d0]);
    zp[0] = make_float4(qp0[0], qp0[1], qp0[2], qp0[3]);
    zp[1] = make_float4(qp0[4], qp0[5], qp0[6], qp0[7]);
  }
  __syncthreads();

#pragma unroll 1
  for (int ev = 0; ev < 4; ++ev) {
    // P1: T-net layer 1 (K=64)
    in_fwd<kDim>(kW1, kb1, zsh, h1, s1, sg, jg);
    __syncthreads();
    // P2: T-net layer 2 fwd -> g2 = sigmoid(a2)*kW3
    mid_fwd(kW2, kb2, kW3, h1, g2, sg, jg);
    __syncthreads();
    // P3: gh1 = (g2 @ kW2) * s1 -> h1
    mid_bwd(kW2, g2, s1, h1, sg, jg);
    __syncthreads();
    // Pgz: gH = gh1 @ kW1   (mapping B)
    {
      float a8[8];
#pragma unroll
      for (int i = 0; i < 8; ++i) a8[i] = 0.f;
#pragma unroll 2
      for (int k = 0; k < kHh; k += 8) {
        float xv8[8];
        upk8(*reinterpret_cast<const uint4*>(&h1[sB][k]), xv8);
#pragma unroll
        for (int kk = 0; kk < 8; ++kk) {
          const float4* wr = reinterpret_cast<const float4*>(&kW1[(size_t)(k+kk)*kDim + d0]);
          float4 w0 = wr[0], w1 = wr[1];
          a8[0] += xv8[kk]*w0.x; a8[1] += xv8[kk]*w0.y;
          a8[2] += xv8[kk]*w0.z; a8[3] += xv8[kk]*w0.w;
          a8[4] += xv8[kk]*w1.x; a8[5] += xv8[kk]*w1.y;
          a8[6] += xv8[kk]*w1.z; a8[7] += xv8[kk]*w1.w;
        }
      }
      float4* gp = reinterpret_cast<float4*>(&gH[sB][d0]);
      gp[0] = make_float4(a8[0], a8[1], a8[2], a8[3]);
      gp[1] = make_float4(a8[4], a8[5], a8[6], a8[7]);
    }
    __syncthreads();
    // P4: V-net layer 1 (K=32, reads q part of z)
    in_fwd<kQd>(vW1, vb1, zsh, h1, s1, sg, jg);
    __syncthreads();
    // P5: V-net layer 2 fwd -> g2
    mid_fwd(vW2, vb2, vW3, h1, g2, sg, jg);
    __syncthreads();
    // P6: gh1v = (g2 @ vW2) * s1 -> h1
    mid_bwd(vW2, g2, s1, h1, sg, jg);
    __syncthreads();
    // Pgq: gH[:, :32] += gh1v @ vW1   (mapping B, 4 dims/thread)
    {
      const int dq0 = dg * 4;
      float a4[4] = {0.f, 0.f, 0.f, 0.f};
#pragma unroll 2
      for (int k = 0; k < kHh; k += 8) {
        float xv8[8];
        upk8(*reinterpret_cast<const uint4*>(&h1[sB][k]), xv8);
#pragma unroll
        for (int kk = 0; kk < 8; ++kk) {
          float4 w = *reinterpret_cast<const float4*>(&vW1[(size_t)(k+kk)*kQd + dq0]);
          a4[0] += xv8[kk]*w.x; a4[1] += xv8[kk]*w.y;
          a4[2] += xv8[kk]*w.z; a4[3] += xv8[kk]*w.w;
        }
      }
#pragma unroll
      for (int t2 = 0; t2 < 4; ++t2) gH[sB][dq0 + t2] += a4[t2];
    }
    __syncthreads();
    // P7: dz = gH @ M^T; Bu add; RK4 update (mapping B)
    {
      float a8[8];
#pragma unroll
      for (int i = 0; i < 8; ++i) a8[i] = 0.f;
#pragma unroll 2
      for (int e = 0; e < kDim; e += 4) {
        float4 xv = *reinterpret_cast<const float4*>(&gH[sB][e]);
#pragma unroll
        for (int dd = 0; dd < 8; ++dd) {
          float4 m = *reinterpret_cast<const float4*>(&M[(size_t)(d0+dd)*kDim + e]);
          a8[dd] += m.x*xv.x + m.y*xv.y + m.z*xv.z + m.w*xv.w;
        }
      }
      const float cstep = (ev == 2) ? kDt : (0.5f * kDt);
      const float wgt   = (ev == 0 || ev == 3) ? 1.0f : 2.0f;
      float zn[8];
#pragma unroll
      for (int dd = 0; dd < 8; ++dd) {
        float v = a8[dd] + u_s * bc8[dd];
        accRK[dd] += wgt * v;
        zn[dd] = qp0[dd] + cstep * v;
      }
      if (ev < 3) {
        float4* zp = reinterpret_cast<float4*>(&zsh[sB][d0]);
        zp[0] = make_float4(zn[0], zn[1], zn[2], zn[3]);
        zp[1] = make_float4(zn[4], zn[5], zn[6], zn[7]);
      }
    }
    __syncthreads();
  }

  {
#pragma unroll
    for (int dd = 0; dd < 8; ++dd) qp0[dd] += (kDt / 6.0f) * accRK[dd];
    float4* p = reinterpret_cast<float4*>(qp + (base + sB) * kDim + d0);
    p[0] = make_float4(qp0[0], qp0[1], qp0[2], qp0[3]);
    p[1] = make_float4(qp0[4], qp0[5], qp0[6], qp0[7]);
  }
}

// ---------------- host ----------------
extern "C" void kernel_launch(void* const* d_in, const int* in_sizes, int n_in,
                              void* d_out, int out_size, void* d_ws, size_t ws_size,
                              hipStream_t stream) {
  const float* h    = (const float*)d_in[0];
  const float* u    = (const float*)d_in[1];
  const float* sW1  = (const float*)d_in[2];
  const float* sb1  = (const float*)d_in[3];
  const float* sW2  = (const float*)d_in[4];
  const float* sb2  = (const float*)d_in[5];
  const float* tW1  = (const float*)d_in[6];
  const float* tb1  = (const float*)d_in[7];
  const float* tW2  = (const float*)d_in[8];
  const float* tb2  = (const float*)d_in[9];
  const float* kW1  = (const float*)d_in[10];
  const float* kb1  = (const float*)d_in[11];
  const float* kW2  = (const float*)d_in[12];
  const float* kb2  = (const float*)d_in[13];
  const float* kW3  = (const float*)d_in[14];
  // kb3 = d_in[15] unused (constant in gradient)
  const float* vW1  = (const float*)d_in[16];
  const float* vb1  = (const float*)d_in[17];
  const float* vW2  = (const float*)d_in[18];
  const float* vb2  = (const float*)d_in[19];
  const float* vW3  = (const float*)d_in[20];
  // vb3 = d_in[21] unused
  const float* A    = (const float*)d_in[22];
  const float* Lp   = (const float*)d_in[23];
  const float* Bc   = (const float*)d_in[24];
  (void)n_in; (void)ws_size;

  float* out = (float*)d_out;
  float* ws  = (float*)d_ws;
  float* M     = ws;                       // 4096 floats
  float* sW2T  = ws + 4096;                // 24576 floats
  float* tW2T  = ws + 4096 + kNl*kHf*kQd;  // 24576 floats

  const int B = in_sizes[0] / kDim;        // 131072
  const int flowGrid = B / 256;            // 512
  const int rkGrid   = B / 32;             // 4096

  prep_M<<<16, 256, 0, stream>>>(A, Lp, M);
  prep_tr<<<(kNl*kHf*kQd + 255)/256, 256, 0, stream>>>(sW2, tW2, sW2T, tW2T);
  flow_kernel<true><<<flowGrid, 256, 0, stream>>>(h, out, sW1, sb1, sW2T, sb2,
                                                  tW1, tb1, tW2T, tb2);
  rk4_kernel<<<rkGrid, 256, 0, stream>>>(out, u, kW1, kb1, kW2, kb2, kW3,
                                         vW1, vb1, vW2, vb2, vW3, Bc, M);
  flow_kernel<false><<<flowGrid, 256, 0, stream>>>(out, out, sW1, sb1, sW2T, sb2,
                                                   tW1, tb1, tW2T, tb2);
  (void)out_size;
}

// Round 2
// 4697.800 us; speedup vs baseline: 3.2056x; 3.2056x over previous
//
#include <hip/hip_runtime.h>
#include <cstdint>
#include <cstddef>

// ---------------------------------------------------------------------------
// HamiltonianFlowModel: flow_fwd -> RK4(grad_H @ M^T) -> flow_inv
// R2: rk4 rebuilt on bf16 MFMA (16x16x32). Flows remain fp32 VALU.
// ---------------------------------------------------------------------------

namespace {
constexpr int kDim = 64;   // DIM
constexpr int kQd  = 32;   // DIM/2
constexpr int kNl  = 6;    // NLAYERS
constexpr int kHf  = 128;  // HF
constexpr int kHh  = 256;  // HH
constexpr float kDt = 0.05f;

// ws layout: bf16 weight region (u16 element offsets)
constexpr size_t oKW1  = 0;        // [256][64]
constexpr size_t oKW1T = 16384;    // [64][256]
constexpr size_t oKW2  = 32768;    // [256][256]
constexpr size_t oKW2T = 98304;    // [256][256]
constexpr size_t oVW1  = 163840;   // [256][32]
constexpr size_t oVW1T = 172032;   // [32][256]
constexpr size_t oVW2  = 180224;   // [256][256]
constexpr size_t oVW2T = 245760;   // [256][256]
constexpr size_t oMb   = 311296;   // [64][64]
constexpr size_t oF32  = 655360;   // byte offset of f32 region (flow W2 transposes)
}

typedef unsigned short u16;
typedef float  f32x4 __attribute__((ext_vector_type(4)));
typedef __bf16 b16x8 __attribute__((ext_vector_type(8)));

// ---------------- helpers ----------------
__device__ __forceinline__ uint32_t f2bf(float f) {
  uint32_t u = __float_as_uint(f);
  return (u + 0x7fffu + ((u >> 16) & 1u)) >> 16;   // RNE bf16
}
__device__ __forceinline__ uint32_t pkbf(float a, float b) {
  return f2bf(a) | (f2bf(b) << 16);
}
__device__ __forceinline__ float bf2f(u16 v) {
  return __uint_as_float(((uint32_t)v) << 16);
}
__device__ __forceinline__ f32x4 mfma16(uint4 a, uint4 b, f32x4 c) {
  return __builtin_amdgcn_mfma_f32_16x16x32_bf16(
      __builtin_bit_cast(b16x8, a), __builtin_bit_cast(b16x8, b), c, 0, 0, 0);
}

// ---------------- prep: bf16 weights (+transposes) and fused M ----------------
__global__ void prep_w(const float* __restrict__ kW1, const float* __restrict__ kW2,
                       const float* __restrict__ vW1, const float* __restrict__ vW2,
                       const float* __restrict__ A,  const float* __restrict__ Lp,
                       u16* __restrict__ wsb) {
  const int n = blockIdx.x * 256 + threadIdx.x;   // grid = 65536 threads exactly
  {
    u16 v = (u16)f2bf(kW2[n]);
    wsb[oKW2 + n] = v;
    wsb[oKW2T + (size_t)(n & 255) * 256 + (n >> 8)] = v;
    u16 w = (u16)f2bf(vW2[n]);
    wsb[oVW2 + n] = w;
    wsb[oVW2T + (size_t)(n & 255) * 256 + (n >> 8)] = w;
  }
  if (n < 16384) {
    u16 v = (u16)f2bf(kW1[n]);
    wsb[oKW1 + n] = v;
    wsb[oKW1T + (size_t)(n & 63) * 256 + (n >> 6)] = v;
  }
  if (n < 8192) {
    u16 v = (u16)f2bf(vW1[n]);
    wsb[oVW1 + n] = v;
    wsb[oVW1T + (size_t)(n & 31) * 256 + (n >> 5)] = v;
  }
  if (n < 4096) {  // M = (A - A^T) - L L^T
    int d = n >> 6, e = n & 63;
    int kmax = min(d, e);
    float sum = 0.f;
    for (int k = 0; k <= kmax; ++k) {
      float ld = (k < d) ? Lp[d * kDim + k] : log1pf(expf(Lp[d * kDim + d]));
      float le = (k < e) ? Lp[e * kDim + k] : log1pf(expf(Lp[e * kDim + e]));
      sum += ld * le;
    }
    wsb[oMb + n] = (u16)f2bf(A[d * kDim + e] - A[e * kDim + d] - sum);
  }
}

// ---------------- prep: transpose flow W2 [6][32][128] -> [6][128][32] ----------------
__global__ void prep_tr(const float* __restrict__ sW2, const float* __restrict__ tW2,
                        float* __restrict__ sW2T, float* __restrict__ tW2T) {
  int n = blockIdx.x * 256 + threadIdx.x;
  if (n >= kNl * kHf * kQd) return;
  int l = n / (kHf * kQd);
  int r = n % (kHf * kQd);
  int j = r / kQd;
  int k = r % kQd;
  sW2T[n] = sW2[l * kQd * kHf + k * kHf + j];
  tW2T[n] = tW2[l * kQd * kHf + k * kHf + j];
}

// ---------------- flow (fwd/inv), thread-per-sample (unchanged, fp32) ----------------
template <bool FWD>
__global__ __launch_bounds__(256, 2)
void flow_kernel(const float* __restrict__ io_in, float* __restrict__ io_out,
                 const float* __restrict__ W1s, const float* __restrict__ b1s,
                 const float* __restrict__ W2Ts, const float* __restrict__ b2s,
                 const float* __restrict__ W1t, const float* __restrict__ b1t,
                 const float* __restrict__ W2Tt, const float* __restrict__ b2t) {
  const size_t s = (size_t)blockIdx.x * blockDim.x + threadIdx.x;
  float x[kDim];
  {
    const float4* p = reinterpret_cast<const float4*>(io_in + s * kDim);
#pragma unroll
    for (int i = 0; i < kDim / 4; ++i) {
      float4 v = p[i];
      x[4*i+0] = v.x; x[4*i+1] = v.y; x[4*i+2] = v.z; x[4*i+3] = v.w;
    }
  }

#define FLOW_LAYER(CB, TB)                                                           \
  do {                                                                               \
    float aS[kQd], aT[kQd];                                                          \
    _Pragma("unroll")                                                                \
    for (int k = 0; k < kQd; ++k) {                                                  \
      aS[k] = b2s[l * kQd + k];                                                      \
      aT[k] = b2t[l * kQd + k];                                                      \
    }                                                                                \
    for (int j = 0; j < kHf; ++j) {                                                  \
      float hs = b1s[l * kHf + j];                                                   \
      float ht = b1t[l * kHf + j];                                                   \
      const float4* w1sp = reinterpret_cast<const float4*>(W1s + ((size_t)l*kHf + j)*kQd); \
      const float4* w1tp = reinterpret_cast<const float4*>(W1t + ((size_t)l*kHf + j)*kQd); \
      _Pragma("unroll")                                                              \
      for (int kk = 0; kk < kQd / 4; ++kk) {                                         \
        float4 ws = w1sp[kk], wt = w1tp[kk];                                         \
        hs += ws.x*x[CB+4*kk+0] + ws.y*x[CB+4*kk+1] + ws.z*x[CB+4*kk+2] + ws.w*x[CB+4*kk+3]; \
        ht += wt.x*x[CB+4*kk+0] + wt.y*x[CB+4*kk+1] + wt.z*x[CB+4*kk+2] + wt.w*x[CB+4*kk+3]; \
      }                                                                              \
      hs = fmaxf(hs, 0.0f); ht = fmaxf(ht, 0.0f);                                    \
      const float4* w2sp = reinterpret_cast<const float4*>(W2Ts + ((size_t)l*kHf + j)*kQd); \
      const float4* w2tp = reinterpret_cast<const float4*>(W2Tt + ((size_t)l*kHf + j)*kQd); \
      _Pragma("unroll")                                                              \
      for (int kk = 0; kk < kQd / 4; ++kk) {                                         \
        float4 vs = w2sp[kk], vt = w2tp[kk];                                         \
        aS[4*kk+0] += vs.x*hs; aS[4*kk+1] += vs.y*hs;                                \
        aS[4*kk+2] += vs.z*hs; aS[4*kk+3] += vs.w*hs;                                \
        aT[4*kk+0] += vt.x*ht; aT[4*kk+1] += vt.y*ht;                                \
        aT[4*kk+2] += vt.z*ht; aT[4*kk+3] += vt.w*ht;                                \
      }                                                                              \
    }                                                                                \
    _Pragma("unroll")                                                                \
    for (int k = 0; k < kQd; ++k) {                                                  \
      float sv = tanhf(aS[k]);                                                       \
      float tv = aT[k];                                                              \
      if (FWD) x[TB + k] = x[TB + k] * __expf(sv) + tv;                              \
      else     x[TB + k] = (x[TB + k] - tv) * __expf(-sv);                           \
    }                                                                                \
  } while (0)

#pragma unroll 1
  for (int li = 0; li < kNl; ++li) {
    const int l = FWD ? li : (kNl - 1 - li);
    if ((l & 1) == 0) { FLOW_LAYER(0, kQd); }
    else              { FLOW_LAYER(kQd, 0); }
  }
#undef FLOW_LAYER

  {
    float4* p = reinterpret_cast<float4*>(io_out + s * kDim);
#pragma unroll
    for (int i = 0; i < kDim / 4; ++i) {
      p[i] = make_float4(x[4*i+0], x[4*i+1], x[4*i+2], x[4*i+3]);
    }
  }
}

// ---------------- RK4 via MFMA ----------------
// Block: 512 threads = 8 waves, 32 samples. Per 256-wide GEMM: wave w owns
// output cols [w*32, w*32+32): 2 m-tiles x 2 n-tiles x K/32 chunks.
// MFMA 16x16x32 layouts: A lane: row=l&15, k=(l>>4)*8+j (contiguous 16B);
// B lane: col=l&15, k=(l>>4)*8+j; C/D lane: col=l&15, row=(l>>4)*4+reg.

__device__ __forceinline__ void gemm256_2x2(const u16* __restrict__ Ab, int lda,
                                            const u16* __restrict__ Wb,
                                            int r, int kg, int n0, f32x4 acc[2][2]) {
#pragma unroll
  for (int kc = 0; kc < 8; ++kc) {
    uint4 b0 = *reinterpret_cast<const uint4*>(Wb + (size_t)(n0 + r) * 256 + kc*32 + kg*8);
    uint4 b1 = *reinterpret_cast<const uint4*>(Wb + (size_t)(n0 + 16 + r) * 256 + kc*32 + kg*8);
    uint4 a0 = *reinterpret_cast<const uint4*>(Ab + (size_t)r * lda + kc*32 + kg*8);
    uint4 a1 = *reinterpret_cast<const uint4*>(Ab + (size_t)(16 + r) * lda + kc*32 + kg*8);
    acc[0][0] = mfma16(a0, b0, acc[0][0]); acc[0][1] = mfma16(a0, b1, acc[0][1]);
    acc[1][0] = mfma16(a1, b0, acc[1][0]); acc[1][1] = mfma16(a1, b1, acc[1][1]);
  }
}

__global__ __launch_bounds__(512, 4)
void rk4_mfma(float* __restrict__ qp, const float* __restrict__ u,
              const u16* __restrict__ wsb,
              const float* __restrict__ kb1, const float* __restrict__ kb2,
              const float* __restrict__ kW3,
              const float* __restrict__ vb1, const float* __restrict__ vb2,
              const float* __restrict__ vW3,
              const float* __restrict__ Bc) {
  __shared__ __align__(16) u16   Zs[32][72];    // z bf16 (pad: stride 144B == 4 mod 32 dw)
  __shared__ __align__(16) u16   B1[32][264];   // h1 / gh1 / h1v / gh1v
  __shared__ __align__(16) u16   B2[32][264];   // g2 / g2v ; f32 dz overlay
  __shared__ __align__(16) float gHs[32][68];   // grad_H f32
  float* dzf = reinterpret_cast<float*>(&B2[0][0]);  // [32][68] f32 (8704B <= 16896B)

  const u16* kW1b  = wsb + oKW1;
  const u16* kW1Tb = wsb + oKW1T;
  const u16* kW2b  = wsb + oKW2;
  const u16* kW2Tb = wsb + oKW2T;
  const u16* vW1b  = wsb + oVW1;
  const u16* vW1Tb = wsb + oVW1T;
  const u16* vW2b  = wsb + oVW2;
  const u16* vW2Tb = wsb + oVW2T;
  const u16* Mb    = wsb + oMb;

  const int tid  = threadIdx.x;
  const int lane = tid & 63, wv = tid >> 6;
  const int r = lane & 15, kg = lane >> 4;
  const int n0 = wv * 32;
  const size_t base = (size_t)blockIdx.x * 32;

  // RK state: thread owns sample s=tid>>4, dims d0..d0+3
  const int s  = tid >> 4;
  const int d0 = (tid & 15) * 4;
  float qp0[4], accRK[4] = {0.f, 0.f, 0.f, 0.f}, bc4[4];
  {
    float4 v = *reinterpret_cast<const float4*>(qp + (base + s) * kDim + d0);
    qp0[0] = v.x; qp0[1] = v.y; qp0[2] = v.z; qp0[3] = v.w;
  }
  const float u_s = u[base + s];
#pragma unroll
  for (int i = 0; i < 4; ++i)
    bc4[i] = (d0 + i >= kQd) ? Bc[d0 + i - kQd] : 0.0f;
  *reinterpret_cast<uint2*>(&Zs[s][d0]) =
      make_uint2(pkbf(qp0[0], qp0[1]), pkbf(qp0[2], qp0[3]));
  __syncthreads();

#pragma unroll 1
  for (int ev = 0; ev < 4; ++ev) {
    { // P1: h1 = softplus(Z @ kW1^T + kb1) -> B1
      f32x4 acc[2][2] = {};
#pragma unroll
      for (int kc = 0; kc < 2; ++kc) {
        uint4 b0 = *reinterpret_cast<const uint4*>(kW1b + (size_t)(n0 + r) * 64 + kc*32 + kg*8);
        uint4 b1 = *reinterpret_cast<const uint4*>(kW1b + (size_t)(n0 + 16 + r) * 64 + kc*32 + kg*8);
        uint4 a0 = *reinterpret_cast<const uint4*>(&Zs[r][kc*32 + kg*8]);
        uint4 a1 = *reinterpret_cast<const uint4*>(&Zs[16 + r][kc*32 + kg*8]);
        acc[0][0] = mfma16(a0,b0,acc[0][0]); acc[0][1] = mfma16(a0,b1,acc[0][1]);
        acc[1][0] = mfma16(a1,b0,acc[1][0]); acc[1][1] = mfma16(a1,b1,acc[1][1]);
      }
      float bn0 = kb1[n0 + r], bn1 = kb1[n0 + 16 + r];
#pragma unroll
      for (int mt = 0; mt < 2; ++mt)
#pragma unroll
        for (int reg = 0; reg < 4; ++reg) {
          int row = mt*16 + kg*4 + reg;
          B1[row][n0 + r]      = (u16)f2bf(__logf(1.f + __expf(acc[mt][0][reg] + bn0)));
          B1[row][n0 + 16 + r] = (u16)f2bf(__logf(1.f + __expf(acc[mt][1][reg] + bn1)));
        }
    }
    __syncthreads();

    { // P2: g2 = sigmoid(h1 @ kW2^T + kb2) * kW3 -> B2
      f32x4 acc[2][2] = {};
      gemm256_2x2(&B1[0][0], 264, kW2b, r, kg, n0, acc);
      float bn0 = kb2[n0 + r], bn1 = kb2[n0 + 16 + r];
      float w30 = kW3[n0 + r], w31 = kW3[n0 + 16 + r];
#pragma unroll
      for (int mt = 0; mt < 2; ++mt)
#pragma unroll
        for (int reg = 0; reg < 4; ++reg) {
          int row = mt*16 + kg*4 + reg;
          B2[row][n0 + r]      = (u16)f2bf(w30 / (1.f + __expf(-(acc[mt][0][reg] + bn0))));
          B2[row][n0 + 16 + r] = (u16)f2bf(w31 / (1.f + __expf(-(acc[mt][1][reg] + bn1))));
        }
    }
    __syncthreads();

    { // P3: gh1 = (g2 @ kW2) * s1, s1 = 1-exp(-h1)  -> B1 in place
      f32x4 acc[2][2] = {};
      gemm256_2x2(&B2[0][0], 264, kW2Tb, r, kg, n0, acc);
#pragma unroll
      for (int mt = 0; mt < 2; ++mt)
#pragma unroll
        for (int nt = 0; nt < 2; ++nt)
#pragma unroll
          for (int reg = 0; reg < 4; ++reg) {
            int row = mt*16 + kg*4 + reg, col = n0 + nt*16 + r;
            float h = bf2f(B1[row][col]);
            B1[row][col] = (u16)f2bf(acc[mt][nt][reg] * (1.f - __expf(-h)));
          }
    }
    __syncthreads();

    { // P4: gHs = gh1 @ kW1  (8 tiles, 1 per wave)
      const int mt = wv >> 2, nt = wv & 3;
      f32x4 acc = {};
#pragma unroll
      for (int kc = 0; kc < 8; ++kc) {
        uint4 b = *reinterpret_cast<const uint4*>(kW1Tb + (size_t)(nt*16 + r) * 256 + kc*32 + kg*8);
        uint4 a = *reinterpret_cast<const uint4*>(&B1[mt*16 + r][kc*32 + kg*8]);
        acc = mfma16(a, b, acc);
      }
#pragma unroll
      for (int reg = 0; reg < 4; ++reg)
        gHs[mt*16 + kg*4 + reg][nt*16 + r] = acc[reg];
    }
    __syncthreads();

    { // P5: h1v = softplus(Zq @ vW1^T + vb1) -> B1   (K=32)
      f32x4 acc[2][2] = {};
      uint4 b0 = *reinterpret_cast<const uint4*>(vW1b + (size_t)(n0 + r) * 32 + kg*8);
      uint4 b1 = *reinterpret_cast<const uint4*>(vW1b + (size_t)(n0 + 16 + r) * 32 + kg*8);
      uint4 a0 = *reinterpret_cast<const uint4*>(&Zs[r][kg*8]);
      uint4 a1 = *reinterpret_cast<const uint4*>(&Zs[16 + r][kg*8]);
      acc[0][0] = mfma16(a0,b0,acc[0][0]); acc[0][1] = mfma16(a0,b1,acc[0][1]);
      acc[1][0] = mfma16(a1,b0,acc[1][0]); acc[1][1] = mfma16(a1,b1,acc[1][1]);
      float bn0 = vb1[n0 + r], bn1 = vb1[n0 + 16 + r];
#pragma unroll
      for (int mt = 0; mt < 2; ++mt)
#pragma unroll
        for (int reg = 0; reg < 4; ++reg) {
          int row = mt*16 + kg*4 + reg;
          B1[row][n0 + r]      = (u16)f2bf(__logf(1.f + __expf(acc[mt][0][reg] + bn0)));
          B1[row][n0 + 16 + r] = (u16)f2bf(__logf(1.f + __expf(acc[mt][1][reg] + bn1)));
        }
    }
    __syncthreads();

    { // P6: g2v = sigmoid(h1v @ vW2^T + vb2) * vW3 -> B2
      f32x4 acc[2][2] = {};
      gemm256_2x2(&B1[0][0], 264, vW2b, r, kg, n0, acc);
      float bn0 = vb2[n0 + r], bn1 = vb2[n0 + 16 + r];
      float w30 = vW3[n0 + r], w31 = vW3[n0 + 16 + r];
#pragma unroll
      for (int mt = 0; mt < 2; ++mt)
#pragma unroll
        for (int reg = 0; reg < 4; ++reg) {
          int row = mt*16 + kg*4 + reg;
          B2[row][n0 + r]      = (u16)f2bf(w30 / (1.f + __expf(-(acc[mt][0][reg] + bn0))));
          B2[row][n0 + 16 + r] = (u16)f2bf(w31 / (1.f + __expf(-(acc[mt][1][reg] + bn1))));
        }
    }
    __syncthreads();

    { // P7: gh1v = (g2v @ vW2) * s1v -> B1 in place
      f32x4 acc[2][2] = {};
      gemm256_2x2(&B2[0][0], 264, vW2Tb, r, kg, n0, acc);
#pragma unroll
      for (int mt = 0; mt < 2; ++mt)
#pragma unroll
        for (int nt = 0; nt < 2; ++nt)
#pragma unroll
          for (int reg = 0; reg < 4; ++reg) {
            int row = mt*16 + kg*4 + reg, col = n0 + nt*16 + r;
            float h = bf2f(B1[row][col]);
            B1[row][col] = (u16)f2bf(acc[mt][nt][reg] * (1.f - __expf(-h)));
          }
    }
    __syncthreads();

    if (wv < 4) { // P8: gHs[:, :32] += gh1v @ vW1  (4 tiles, waves 0-3)
      const int mt = wv >> 1, nt = wv & 1;
      f32x4 acc = {};
#pragma unroll
      for (int kc = 0; kc < 8; ++kc) {
        uint4 b = *reinterpret_cast<const uint4*>(vW1Tb + (size_t)(nt*16 + r) * 256 + kc*32 + kg*8);
        uint4 a = *reinterpret_cast<const uint4*>(&B1[mt*16 + r][kc*32 + kg*8]);
        acc = mfma16(a, b, acc);
      }
#pragma unroll
      for (int reg = 0; reg < 4; ++reg)
        gHs[mt*16 + kg*4 + reg][nt*16 + r] += acc[reg];
    }
    __syncthreads();

    { // P9: dz = gH @ M^T -> dzf (f32 over B2; B2 dead since P7 barrier)
      const int mt = wv >> 2, nt = wv & 3;
      f32x4 acc = {};
#pragma unroll
      for (int kc = 0; kc < 2; ++kc) {
        const float* gp = &gHs[mt*16 + r][kc*32 + kg*8];
        float4 ga = *reinterpret_cast<const float4*>(gp);
        float4 gb = *reinterpret_cast<const float4*>(gp + 4);
        uint4 a = make_uint4(pkbf(ga.x, ga.y), pkbf(ga.z, ga.w),
                             pkbf(gb.x, gb.y), pkbf(gb.z, gb.w));
        uint4 b = *reinterpret_cast<const uint4*>(Mb + (size_t)(nt*16 + r) * 64 + kc*32 + kg*8);
        acc = mfma16(a, b, acc);
      }
#pragma unroll
      for (int reg = 0; reg < 4; ++reg)
        dzf[(size_t)(mt*16 + kg*4 + reg) * 68 + nt*16 + r] = acc[reg];
    }
    __syncthreads();

    { // RK update (thread-owned dims)
      const float cstep = (ev == 2) ? kDt : (0.5f * kDt);
      const float wgt   = (ev == 0 || ev == 3) ? 1.0f : 2.0f;
      float4 dv = *reinterpret_cast<const float4*>(dzf + (size_t)s * 68 + d0);
      float vv[4] = {dv.x, dv.y, dv.z, dv.w};
      float zn[4];
#pragma unroll
      for (int i = 0; i < 4; ++i) {
        vv[i] += u_s * bc4[i];
        accRK[i] += wgt * vv[i];
        zn[i] = qp0[i] + cstep * vv[i];
      }
      if (ev < 3)
        *reinterpret_cast<uint2*>(&Zs[s][d0]) =
            make_uint2(pkbf(zn[0], zn[1]), pkbf(zn[2], zn[3]));
    }
    __syncthreads();
  }

  {
#pragma unroll
    for (int i = 0; i < 4; ++i) qp0[i] += (kDt / 6.0f) * accRK[i];
    *reinterpret_cast<float4*>(qp + (base + s) * kDim + d0) =
        make_float4(qp0[0], qp0[1], qp0[2], qp0[3]);
  }
}

// ---------------- host ----------------
extern "C" void kernel_launch(void* const* d_in, const int* in_sizes, int n_in,
                              void* d_out, int out_size, void* d_ws, size_t ws_size,
                              hipStream_t stream) {
  const float* h    = (const float*)d_in[0];
  const float* u    = (const float*)d_in[1];
  const float* sW1  = (const float*)d_in[2];
  const float* sb1  = (const float*)d_in[3];
  const float* sW2  = (const float*)d_in[4];
  const float* sb2  = (const float*)d_in[5];
  const float* tW1  = (const float*)d_in[6];
  const float* tb1  = (const float*)d_in[7];
  const float* tW2  = (const float*)d_in[8];
  const float* tb2  = (const float*)d_in[9];
  const float* kW1  = (const float*)d_in[10];
  const float* kb1  = (const float*)d_in[11];
  const float* kW2  = (const float*)d_in[12];
  const float* kb2  = (const float*)d_in[13];
  const float* kW3  = (const float*)d_in[14];
  const float* vW1  = (const float*)d_in[16];
  const float* vb1  = (const float*)d_in[17];
  const float* vW2  = (const float*)d_in[18];
  const float* vb2  = (const float*)d_in[19];
  const float* vW3  = (const float*)d_in[20];
  const float* A    = (const float*)d_in[22];
  const float* Lp   = (const float*)d_in[23];
  const float* Bc   = (const float*)d_in[24];
  (void)n_in; (void)ws_size; (void)out_size;

  float* out = (float*)d_out;
  u16*   wsb = (u16*)d_ws;
  float* fw  = (float*)((char*)d_ws + oF32);
  float* sW2T = fw;
  float* tW2T = fw + (size_t)kNl * kHf * kQd;

  const int B = in_sizes[0] / kDim;        // 131072
  const int flowGrid = B / 256;            // 512
  const int rkGrid   = B / 32;             // 4096

  prep_w<<<256, 256, 0, stream>>>(kW1, kW2, vW1, vW2, A, Lp, wsb);
  prep_tr<<<(kNl*kHf*kQd + 255)/256, 256, 0, stream>>>(sW2, tW2, sW2T, tW2T);
  flow_kernel<true><<<flowGrid, 256, 0, stream>>>(h, out, sW1, sb1, sW2T, sb2,
                                                  tW1, tb1, tW2T, tb2);
  rk4_mfma<<<rkGrid, 512, 0, stream>>>(out, u, wsb, kb1, kb2, kW3,
                                       vb1, vb2, vW3, Bc);
  flow_kernel<false><<<flowGrid, 256, 0, stream>>>(out, out, sW1, sb1, sW2T, sb2,
                                                   tW1, tb1, tW2T, tb2);
}

// Round 3
// 2607.234 us; speedup vs baseline: 5.7760x; 1.8018x over previous
//
#include <hip/hip_runtime.h>
#include <cstdint>
#include <cstddef>

// ---------------------------------------------------------------------------
// HamiltonianFlowModel: flow_fwd -> RK4(grad_H @ M^T) -> flow_inv
// R3: nt (non-temporal) hints on use-once streams; flows rewritten on MFMA.
// ---------------------------------------------------------------------------

namespace {
constexpr int kDim = 64;   // DIM
constexpr int kQd  = 32;   // DIM/2
constexpr int kNl  = 6;    // NLAYERS
constexpr float kDt = 0.05f;

// ws layout (u16 element offsets)
constexpr size_t oKW1  = 0;        // [256][64]
constexpr size_t oKW1T = 16384;    // [64][256]
constexpr size_t oKW2  = 32768;    // [256][256]
constexpr size_t oKW2T = 98304;    // [256][256]
constexpr size_t oVW1  = 163840;   // [256][32]
constexpr size_t oVW1T = 172032;   // [32][256]
constexpr size_t oVW2  = 180224;   // [256][256]
constexpr size_t oVW2T = 245760;   // [256][256]
constexpr size_t oMb   = 311296;   // [64][64]
constexpr size_t oSW1  = 315392;   // [6][128][32]
constexpr size_t oTW1  = 339968;   // [6][128][32]
constexpr size_t oSW2  = 364544;   // [6][32][128]
constexpr size_t oTW2  = 389120;   // [6][32][128]
}

typedef unsigned short u16;
typedef float  f32x4 __attribute__((ext_vector_type(4)));
typedef __bf16 b16x8 __attribute__((ext_vector_type(8)));

// ---------------- helpers ----------------
__device__ __forceinline__ uint32_t f2bf(float f) {
  uint32_t u = __float_as_uint(f);
  return (u + 0x7fffu + ((u >> 16) & 1u)) >> 16;   // RNE bf16
}
__device__ __forceinline__ uint32_t pkbf(float a, float b) {
  return f2bf(a) | (f2bf(b) << 16);
}
__device__ __forceinline__ float bf2f(u16 v) {
  return __uint_as_float(((uint32_t)v) << 16);
}
__device__ __forceinline__ f32x4 mfma16(uint4 a, uint4 b, f32x4 c) {
  return __builtin_amdgcn_mfma_f32_16x16x32_bf16(
      __builtin_bit_cast(b16x8, a), __builtin_bit_cast(b16x8, b), c, 0, 0, 0);
}
__device__ __forceinline__ f32x4 ntld4(const float* p) {
  return __builtin_nontemporal_load(reinterpret_cast<const f32x4*>(p));
}
__device__ __forceinline__ void ntst4(float* p, f32x4 v) {
  __builtin_nontemporal_store(v, reinterpret_cast<f32x4*>(p));
}

// ---------------- prep: bf16 weights (+transposes) and fused M ----------------
__global__ void prep_w(const float* __restrict__ kW1, const float* __restrict__ kW2,
                       const float* __restrict__ vW1, const float* __restrict__ vW2,
                       const float* __restrict__ A,  const float* __restrict__ Lp,
                       const float* __restrict__ sW1, const float* __restrict__ tW1,
                       const float* __restrict__ sW2, const float* __restrict__ tW2,
                       u16* __restrict__ wsb) {
  const int n = blockIdx.x * 256 + threadIdx.x;   // grid = 65536 threads exactly
  {
    u16 v = (u16)f2bf(kW2[n]);
    wsb[oKW2 + n] = v;
    wsb[oKW2T + (size_t)(n & 255) * 256 + (n >> 8)] = v;
    u16 w = (u16)f2bf(vW2[n]);
    wsb[oVW2 + n] = w;
    wsb[oVW2T + (size_t)(n & 255) * 256 + (n >> 8)] = w;
  }
  if (n < 24576) {
    wsb[oSW1 + n] = (u16)f2bf(sW1[n]);
    wsb[oTW1 + n] = (u16)f2bf(tW1[n]);
    wsb[oSW2 + n] = (u16)f2bf(sW2[n]);
    wsb[oTW2 + n] = (u16)f2bf(tW2[n]);
  }
  if (n < 16384) {
    u16 v = (u16)f2bf(kW1[n]);
    wsb[oKW1 + n] = v;
    wsb[oKW1T + (size_t)(n & 63) * 256 + (n >> 6)] = v;
  }
  if (n < 8192) {
    u16 v = (u16)f2bf(vW1[n]);
    wsb[oVW1 + n] = v;
    wsb[oVW1T + (size_t)(n & 31) * 256 + (n >> 5)] = v;
  }
  if (n < 4096) {  // M = (A - A^T) - L L^T
    int d = n >> 6, e = n & 63;
    int kmax = min(d, e);
    float sum = 0.f;
    for (int k = 0; k <= kmax; ++k) {
      float ld = (k < d) ? Lp[d * kDim + k] : log1pf(expf(Lp[d * kDim + d]));
      float le = (k < e) ? Lp[e * kDim + k] : log1pf(expf(Lp[e * kDim + e]));
      sum += ld * le;
    }
    wsb[oMb + n] = (u16)f2bf(A[d * kDim + e] - A[e * kDim + d] - sum);
  }
}

// ---------------- flow (fwd/inv) via MFMA ----------------
// 512 threads = 8 waves, 32 samples/block. fp32 x-state in LDS; bf16 operands.
template <bool FWD>
__global__ __launch_bounds__(512, 4)
void flow_mfma(const float* __restrict__ io_in, float* __restrict__ io_out,
               const u16* __restrict__ wsb,
               const float* __restrict__ b1s, const float* __restrict__ b2s,
               const float* __restrict__ b1t, const float* __restrict__ b2t) {
  __shared__ __align__(16) float Xs[32][68];     // fp32 state
  __shared__ __align__(16) u16   CondB[32][40];  // bf16 cond half
  __shared__ __align__(16) u16   H1[32][264];    // relu hidden, cols 0-127 s, 128-255 t
  __shared__ __align__(16) float Sv[32][36];
  __shared__ __align__(16) float Tv[32][36];

  const u16* W1s = wsb + oSW1;  // [6][128][32]
  const u16* W1t = wsb + oTW1;
  const u16* W2s = wsb + oSW2;  // [6][32][128]
  const u16* W2t = wsb + oTW2;

  const int tid  = threadIdx.x;
  const int lane = tid & 63, wv = tid >> 6;
  const int r = lane & 15, kg = lane >> 4;
  const size_t base = (size_t)blockIdx.x * 32;
  const int sm = tid >> 4, quad = tid & 15;       // io mapping: 1 float4/thread

  {
    f32x4 v = ntld4(io_in + (base + sm) * kDim + quad * 4);
    *reinterpret_cast<f32x4*>(&Xs[sm][quad * 4]) = v;
  }
  __syncthreads();

#pragma unroll 1
  for (int li = 0; li < kNl; ++li) {
    const int l = FWD ? li : (kNl - 1 - li);
    const int par = l & 1;
    const int cb = par ? kQd : 0;   // cond base col
    const int tb = par ? 0 : kQd;   // transform base col

    { // build bf16 cond
      int idx = tid * 2, s = idx >> 5, c = idx & 31;
      *reinterpret_cast<uint32_t*>(&CondB[s][c]) = pkbf(Xs[s][cb + c], Xs[s][cb + c + 1]);
    }
    __syncthreads();

    { // GEMM1: [32x32] @ W1^T -> relu -> H1 (s-net waves 0-3, t-net waves 4-7)
      const int net = wv >> 2;
      const int nc0 = (wv & 3) * 32;
      const u16* W1 = net ? W1t : W1s;
      const float* b1 = net ? b1t : b1s;
      uint4 b0 = *reinterpret_cast<const uint4*>(W1 + ((size_t)l*128 + nc0 + r) * 32 + kg*8);
      uint4 b1v = *reinterpret_cast<const uint4*>(W1 + ((size_t)l*128 + nc0 + 16 + r) * 32 + kg*8);
      uint4 a0 = *reinterpret_cast<const uint4*>(&CondB[r][kg*8]);
      uint4 a1 = *reinterpret_cast<const uint4*>(&CondB[16 + r][kg*8]);
      f32x4 acc[2][2] = {};
      acc[0][0] = mfma16(a0,b0,acc[0][0]); acc[0][1] = mfma16(a0,b1v,acc[0][1]);
      acc[1][0] = mfma16(a1,b0,acc[1][0]); acc[1][1] = mfma16(a1,b1v,acc[1][1]);
      float bn0 = b1[l*128 + nc0 + r], bn1 = b1[l*128 + nc0 + 16 + r];
      const int colbase = net * 128 + nc0;
#pragma unroll
      for (int mt = 0; mt < 2; ++mt)
#pragma unroll
        for (int reg = 0; reg < 4; ++reg) {
          int row = mt*16 + kg*4 + reg;
          H1[row][colbase + r]      = (u16)f2bf(fmaxf(acc[mt][0][reg] + bn0, 0.f));
          H1[row][colbase + 16 + r] = (u16)f2bf(fmaxf(acc[mt][1][reg] + bn1, 0.f));
        }
    }
    __syncthreads();

    { // GEMM2: [32x128] @ W2^T -> Sv (tanh+b2s) / Tv (+b2t)
      const int net = wv >> 2, mt = (wv >> 1) & 1, nt2 = wv & 1;
      const u16* W2 = net ? W2t : W2s;
      f32x4 acc = {};
#pragma unroll
      for (int kc = 0; kc < 4; ++kc) {
        uint4 a = *reinterpret_cast<const uint4*>(&H1[mt*16 + r][net*128 + kc*32 + kg*8]);
        uint4 b = *reinterpret_cast<const uint4*>(W2 + ((size_t)l*32 + nt2*16 + r) * 128 + kc*32 + kg*8);
        acc = mfma16(a, b, acc);
      }
      if (net == 0) {
        float b2 = b2s[l*32 + nt2*16 + r];
#pragma unroll
        for (int reg = 0; reg < 4; ++reg)
          Sv[mt*16 + kg*4 + reg][nt2*16 + r] = tanhf(acc[reg] + b2);
      } else {
        float b2 = b2t[l*32 + nt2*16 + r];
#pragma unroll
        for (int reg = 0; reg < 4; ++reg)
          Tv[mt*16 + kg*4 + reg][nt2*16 + r] = acc[reg] + b2;
      }
    }
    __syncthreads();

    { // update transformed half
#pragma unroll
      for (int it = 0; it < 2; ++it) {
        int idx = tid + it * 512, s = idx >> 5, d = idx & 31;
        float sv = Sv[s][d], tv = Tv[s][d];
        float x = Xs[s][tb + d];
        Xs[s][tb + d] = FWD ? (x * __expf(sv) + tv) : ((x - tv) * __expf(-sv));
      }
    }
    __syncthreads();
  }

  {
    f32x4 v = *reinterpret_cast<const f32x4*>(&Xs[sm][quad * 4]);
    ntst4(io_out + (base + sm) * kDim + quad * 4, v);
  }
}

// ---------------- RK4 via MFMA (R2 structure + nt streams) ----------------
__device__ __forceinline__ void gemm256_2x2(const u16* __restrict__ Ab, int lda,
                                            const u16* __restrict__ Wb,
                                            int r, int kg, int n0, f32x4 acc[2][2]) {
#pragma unroll
  for (int kc = 0; kc < 8; ++kc) {
    uint4 b0 = *reinterpret_cast<const uint4*>(Wb + (size_t)(n0 + r) * 256 + kc*32 + kg*8);
    uint4 b1 = *reinterpret_cast<const uint4*>(Wb + (size_t)(n0 + 16 + r) * 256 + kc*32 + kg*8);
    uint4 a0 = *reinterpret_cast<const uint4*>(Ab + (size_t)r * lda + kc*32 + kg*8);
    uint4 a1 = *reinterpret_cast<const uint4*>(Ab + (size_t)(16 + r) * lda + kc*32 + kg*8);
    acc[0][0] = mfma16(a0, b0, acc[0][0]); acc[0][1] = mfma16(a0, b1, acc[0][1]);
    acc[1][0] = mfma16(a1, b0, acc[1][0]); acc[1][1] = mfma16(a1, b1, acc[1][1]);
  }
}

__global__ __launch_bounds__(512, 4)
void rk4_mfma(float* __restrict__ qp, const float* __restrict__ u,
              const u16* __restrict__ wsb,
              const float* __restrict__ kb1, const float* __restrict__ kb2,
              const float* __restrict__ kW3,
              const float* __restrict__ vb1, const float* __restrict__ vb2,
              const float* __restrict__ vW3,
              const float* __restrict__ Bc) {
  __shared__ __align__(16) u16   Zs[32][72];
  __shared__ __align__(16) u16   B1[32][264];
  __shared__ __align__(16) u16   B2[32][264];
  __shared__ __align__(16) float gHs[32][68];
  float* dzf = reinterpret_cast<float*>(&B2[0][0]);  // f32 [32][68] overlay

  const u16* kW1b  = wsb + oKW1;
  const u16* kW1Tb = wsb + oKW1T;
  const u16* kW2b  = wsb + oKW2;
  const u16* kW2Tb = wsb + oKW2T;
  const u16* vW1b  = wsb + oVW1;
  const u16* vW1Tb = wsb + oVW1T;
  const u16* vW2b  = wsb + oVW2;
  const u16* vW2Tb = wsb + oVW2T;
  const u16* Mb    = wsb + oMb;

  const int tid  = threadIdx.x;
  const int lane = tid & 63, wv = tid >> 6;
  const int r = lane & 15, kg = lane >> 4;
  const int n0 = wv * 32;
  const size_t base = (size_t)blockIdx.x * 32;

  const int s  = tid >> 4;
  const int d0 = (tid & 15) * 4;
  float qp0[4], accRK[4] = {0.f, 0.f, 0.f, 0.f}, bc4[4];
  {
    f32x4 v = ntld4(qp + (base + s) * kDim + d0);
    qp0[0] = v.x; qp0[1] = v.y; qp0[2] = v.z; qp0[3] = v.w;
  }
  const float u_s = __builtin_nontemporal_load(u + base + s);
#pragma unroll
  for (int i = 0; i < 4; ++i)
    bc4[i] = (d0 + i >= kQd) ? Bc[d0 + i - kQd] : 0.0f;
  *reinterpret_cast<uint2*>(&Zs[s][d0]) =
      make_uint2(pkbf(qp0[0], qp0[1]), pkbf(qp0[2], qp0[3]));
  __syncthreads();

#pragma unroll 1
  for (int ev = 0; ev < 4; ++ev) {
    { // P1: h1 = softplus(Z @ kW1^T + kb1) -> B1
      f32x4 acc[2][2] = {};
#pragma unroll
      for (int kc = 0; kc < 2; ++kc) {
        uint4 b0 = *reinterpret_cast<const uint4*>(kW1b + (size_t)(n0 + r) * 64 + kc*32 + kg*8);
        uint4 b1 = *reinterpret_cast<const uint4*>(kW1b + (size_t)(n0 + 16 + r) * 64 + kc*32 + kg*8);
        uint4 a0 = *reinterpret_cast<const uint4*>(&Zs[r][kc*32 + kg*8]);
        uint4 a1 = *reinterpret_cast<const uint4*>(&Zs[16 + r][kc*32 + kg*8]);
        acc[0][0] = mfma16(a0,b0,acc[0][0]); acc[0][1] = mfma16(a0,b1,acc[0][1]);
        acc[1][0] = mfma16(a1,b0,acc[1][0]); acc[1][1] = mfma16(a1,b1,acc[1][1]);
      }
      float bn0 = kb1[n0 + r], bn1 = kb1[n0 + 16 + r];
#pragma unroll
      for (int mt = 0; mt < 2; ++mt)
#pragma unroll
        for (int reg = 0; reg < 4; ++reg) {
          int row = mt*16 + kg*4 + reg;
          B1[row][n0 + r]      = (u16)f2bf(__logf(1.f + __expf(acc[mt][0][reg] + bn0)));
          B1[row][n0 + 16 + r] = (u16)f2bf(__logf(1.f + __expf(acc[mt][1][reg] + bn1)));
        }
    }
    __syncthreads();

    { // P2: g2 = sigmoid(h1 @ kW2^T + kb2) * kW3 -> B2
      f32x4 acc[2][2] = {};
      gemm256_2x2(&B1[0][0], 264, kW2b, r, kg, n0, acc);
      float bn0 = kb2[n0 + r], bn1 = kb2[n0 + 16 + r];
      float w30 = kW3[n0 + r], w31 = kW3[n0 + 16 + r];
#pragma unroll
      for (int mt = 0; mt < 2; ++mt)
#pragma unroll
        for (int reg = 0; reg < 4; ++reg) {
          int row = mt*16 + kg*4 + reg;
          B2[row][n0 + r]      = (u16)f2bf(w30 / (1.f + __expf(-(acc[mt][0][reg] + bn0))));
          B2[row][n0 + 16 + r] = (u16)f2bf(w31 / (1.f + __expf(-(acc[mt][1][reg] + bn1))));
        }
    }
    __syncthreads();

    { // P3: gh1 = (g2 @ kW2) * s1, s1 = 1-exp(-h1)  -> B1 in place
      f32x4 acc[2][2] = {};
      gemm256_2x2(&B2[0][0], 264, kW2Tb, r, kg, n0, acc);
#pragma unroll
      for (int mt = 0; mt < 2; ++mt)
#pragma unroll
        for (int nt = 0; nt < 2; ++nt)
#pragma unroll
          for (int reg = 0; reg < 4; ++reg) {
            int row = mt*16 + kg*4 + reg, col = n0 + nt*16 + r;
            float h = bf2f(B1[row][col]);
            B1[row][col] = (u16)f2bf(acc[mt][nt][reg] * (1.f - __expf(-h)));
          }
    }
    __syncthreads();

    { // P4: gHs = gh1 @ kW1
      const int mt = wv >> 2, nt = wv & 3;
      f32x4 acc = {};
#pragma unroll
      for (int kc = 0; kc < 8; ++kc) {
        uint4 b = *reinterpret_cast<const uint4*>(kW1Tb + (size_t)(nt*16 + r) * 256 + kc*32 + kg*8);
        uint4 a = *reinterpret_cast<const uint4*>(&B1[mt*16 + r][kc*32 + kg*8]);
        acc = mfma16(a, b, acc);
      }
#pragma unroll
      for (int reg = 0; reg < 4; ++reg)
        gHs[mt*16 + kg*4 + reg][nt*16 + r] = acc[reg];
    }
    __syncthreads();

    { // P5: h1v = softplus(Zq @ vW1^T + vb1) -> B1   (K=32)
      f32x4 acc[2][2] = {};
      uint4 b0 = *reinterpret_cast<const uint4*>(vW1b + (size_t)(n0 + r) * 32 + kg*8);
      uint4 b1 = *reinterpret_cast<const uint4*>(vW1b + (size_t)(n0 + 16 + r) * 32 + kg*8);
      uint4 a0 = *reinterpret_cast<const uint4*>(&Zs[r][kg*8]);
      uint4 a1 = *reinterpret_cast<const uint4*>(&Zs[16 + r][kg*8]);
      acc[0][0] = mfma16(a0,b0,acc[0][0]); acc[0][1] = mfma16(a0,b1,acc[0][1]);
      acc[1][0] = mfma16(a1,b0,acc[1][0]); acc[1][1] = mfma16(a1,b1,acc[1][1]);
      float bn0 = vb1[n0 + r], bn1 = vb1[n0 + 16 + r];
#pragma unroll
      for (int mt = 0; mt < 2; ++mt)
#pragma unroll
        for (int reg = 0; reg < 4; ++reg) {
          int row = mt*16 + kg*4 + reg;
          B1[row][n0 + r]      = (u16)f2bf(__logf(1.f + __expf(acc[mt][0][reg] + bn0)));
          B1[row][n0 + 16 + r] = (u16)f2bf(__logf(1.f + __expf(acc[mt][1][reg] + bn1)));
        }
    }
    __syncthreads();

    { // P6: g2v = sigmoid(h1v @ vW2^T + vb2) * vW3 -> B2
      f32x4 acc[2][2] = {};
      gemm256_2x2(&B1[0][0], 264, vW2b, r, kg, n0, acc);
      float bn0 = vb2[n0 + r], bn1 = vb2[n0 + 16 + r];
      float w30 = vW3[n0 + r], w31 = vW3[n0 + 16 + r];
#pragma unroll
      for (int mt = 0; mt < 2; ++mt)
#pragma unroll
        for (int reg = 0; reg < 4; ++reg) {
          int row = mt*16 + kg*4 + reg;
          B2[row][n0 + r]      = (u16)f2bf(w30 / (1.f + __expf(-(acc[mt][0][reg] + bn0))));
          B2[row][n0 + 16 + r] = (u16)f2bf(w31 / (1.f + __expf(-(acc[mt][1][reg] + bn1))));
        }
    }
    __syncthreads();

    { // P7: gh1v = (g2v @ vW2) * s1v -> B1 in place
      f32x4 acc[2][2] = {};
      gemm256_2x2(&B2[0][0], 264, vW2Tb, r, kg, n0, acc);
#pragma unroll
      for (int mt = 0; mt < 2; ++mt)
#pragma unroll
        for (int nt = 0; nt < 2; ++nt)
#pragma unroll
          for (int reg = 0; reg < 4; ++reg) {
            int row = mt*16 + kg*4 + reg, col = n0 + nt*16 + r;
            float h = bf2f(B1[row][col]);
            B1[row][col] = (u16)f2bf(acc[mt][nt][reg] * (1.f - __expf(-h)));
          }
    }
    __syncthreads();

    if (wv < 4) { // P8: gHs[:, :32] += gh1v @ vW1
      const int mt = wv >> 1, nt = wv & 1;
      f32x4 acc = {};
#pragma unroll
      for (int kc = 0; kc < 8; ++kc) {
        uint4 b = *reinterpret_cast<const uint4*>(vW1Tb + (size_t)(nt*16 + r) * 256 + kc*32 + kg*8);
        uint4 a = *reinterpret_cast<const uint4*>(&B1[mt*16 + r][kc*32 + kg*8]);
        acc = mfma16(a, b, acc);
      }
#pragma unroll
      for (int reg = 0; reg < 4; ++reg)
        gHs[mt*16 + kg*4 + reg][nt*16 + r] += acc[reg];
    }
    __syncthreads();

    { // P9: dz = gH @ M^T -> dzf
      const int mt = wv >> 2, nt = wv & 3;
      f32x4 acc = {};
#pragma unroll
      for (int kc = 0; kc < 2; ++kc) {
        const float* gp = &gHs[mt*16 + r][kc*32 + kg*8];
        float4 ga = *reinterpret_cast<const float4*>(gp);
        float4 gb = *reinterpret_cast<const float4*>(gp + 4);
        uint4 a = make_uint4(pkbf(ga.x, ga.y), pkbf(ga.z, ga.w),
                             pkbf(gb.x, gb.y), pkbf(gb.z, gb.w));
        uint4 b = *reinterpret_cast<const uint4*>(Mb + (size_t)(nt*16 + r) * 64 + kc*32 + kg*8);
        acc = mfma16(a, b, acc);
      }
#pragma unroll
      for (int reg = 0; reg < 4; ++reg)
        dzf[(size_t)(mt*16 + kg*4 + reg) * 68 + nt*16 + r] = acc[reg];
    }
    __syncthreads();

    { // RK update
      const float cstep = (ev == 2) ? kDt : (0.5f * kDt);
      const float wgt   = (ev == 0 || ev == 3) ? 1.0f : 2.0f;
      float4 dv = *reinterpret_cast<const float4*>(dzf + (size_t)s * 68 + d0);
      float vv[4] = {dv.x, dv.y, dv.z, dv.w};
      float zn[4];
#pragma unroll
      for (int i = 0; i < 4; ++i) {
        vv[i] += u_s * bc4[i];
        accRK[i] += wgt * vv[i];
        zn[i] = qp0[i] + cstep * vv[i];
      }
      if (ev < 3)
        *reinterpret_cast<uint2*>(&Zs[s][d0]) =
            make_uint2(pkbf(zn[0], zn[1]), pkbf(zn[2], zn[3]));
    }
    __syncthreads();
  }

  {
    f32x4 v;
#pragma unroll
    for (int i = 0; i < 4; ++i) v[i] = qp0[i] + (kDt / 6.0f) * accRK[i];
    ntst4(qp + (base + s) * kDim + d0, v);
  }
}

// ---------------- host ----------------
extern "C" void kernel_launch(void* const* d_in, const int* in_sizes, int n_in,
                              void* d_out, int out_size, void* d_ws, size_t ws_size,
                              hipStream_t stream) {
  const float* h    = (const float*)d_in[0];
  const float* u    = (const float*)d_in[1];
  const float* sW1  = (const float*)d_in[2];
  const float* sb1  = (const float*)d_in[3];
  const float* sW2  = (const float*)d_in[4];
  const float* sb2  = (const float*)d_in[5];
  const float* tW1  = (const float*)d_in[6];
  const float* tb1  = (const float*)d_in[7];
  const float* tW2  = (const float*)d_in[8];
  const float* tb2  = (const float*)d_in[9];
  const float* kW1  = (const float*)d_in[10];
  const float* kb1  = (const float*)d_in[11];
  const float* kW2  = (const float*)d_in[12];
  const float* kb2  = (const float*)d_in[13];
  const float* kW3  = (const float*)d_in[14];
  const float* vW1  = (const float*)d_in[16];
  const float* vb1  = (const float*)d_in[17];
  const float* vW2  = (const float*)d_in[18];
  const float* vb2  = (const float*)d_in[19];
  const float* vW3  = (const float*)d_in[20];
  const float* A    = (const float*)d_in[22];
  const float* Lp   = (const float*)d_in[23];
  const float* Bc   = (const float*)d_in[24];
  (void)n_in; (void)ws_size; (void)out_size;

  float* out = (float*)d_out;
  u16*   wsb = (u16*)d_ws;

  const int B = in_sizes[0] / kDim;        // 131072
  const int grid32 = B / 32;               // 4096

  prep_w<<<256, 256, 0, stream>>>(kW1, kW2, vW1, vW2, A, Lp, sW1, tW1, sW2, tW2, wsb);
  flow_mfma<true><<<grid32, 512, 0, stream>>>(h, out, wsb, sb1, sb2, tb1, tb2);
  rk4_mfma<<<grid32, 512, 0, stream>>>(out, u, wsb, kb1, kb2, kW3,
                                       vb1, vb2, vW3, Bc);
  flow_mfma<false><<<grid32, 512, 0, stream>>>(out, out, wsb, sb1, sb2, tb1, tb2);
}

// Round 4
// 2101.588 us; speedup vs baseline: 7.1657x; 1.2406x over previous
//
#include <hip/hip_runtime.h>
#include <cstdint>
#include <cstddef>

// ---------------------------------------------------------------------------
// HamiltonianFlowModel: flow_fwd -> RK4(grad_H @ M^T) -> flow_inv
// R4: fix VGPR cap (launch_bounds 512,2) -> eliminate scratch spills.
// ---------------------------------------------------------------------------

namespace {
constexpr int kDim = 64;   // DIM
constexpr int kQd  = 32;   // DIM/2
constexpr int kNl  = 6;    // NLAYERS
constexpr float kDt = 0.05f;

// ws layout (u16 element offsets)
constexpr size_t oKW1  = 0;        // [256][64]
constexpr size_t oKW1T = 16384;    // [64][256]
constexpr size_t oKW2  = 32768;    // [256][256]
constexpr size_t oKW2T = 98304;    // [256][256]
constexpr size_t oVW1  = 163840;   // [256][32]
constexpr size_t oVW1T = 172032;   // [32][256]
constexpr size_t oVW2  = 180224;   // [256][256]
constexpr size_t oVW2T = 245760;   // [256][256]
constexpr size_t oMb   = 311296;   // [64][64]
constexpr size_t oSW1  = 315392;   // [6][128][32]
constexpr size_t oTW1  = 339968;   // [6][128][32]
constexpr size_t oSW2  = 364544;   // [6][32][128]
constexpr size_t oTW2  = 389120;   // [6][32][128]
}

typedef unsigned short u16;
typedef float  f32x4 __attribute__((ext_vector_type(4)));
typedef __bf16 b16x8 __attribute__((ext_vector_type(8)));

// ---------------- helpers ----------------
__device__ __forceinline__ uint32_t f2bf(float f) {
  uint32_t u = __float_as_uint(f);
  return (u + 0x7fffu + ((u >> 16) & 1u)) >> 16;   // RNE bf16
}
__device__ __forceinline__ uint32_t pkbf(float a, float b) {
  return f2bf(a) | (f2bf(b) << 16);
}
__device__ __forceinline__ float bf2f(u16 v) {
  return __uint_as_float(((uint32_t)v) << 16);
}
__device__ __forceinline__ f32x4 mfma16(uint4 a, uint4 b, f32x4 c) {
  return __builtin_amdgcn_mfma_f32_16x16x32_bf16(
      __builtin_bit_cast(b16x8, a), __builtin_bit_cast(b16x8, b), c, 0, 0, 0);
}
__device__ __forceinline__ f32x4 ntld4(const float* p) {
  return __builtin_nontemporal_load(reinterpret_cast<const f32x4*>(p));
}
__device__ __forceinline__ void ntst4(float* p, f32x4 v) {
  __builtin_nontemporal_store(v, reinterpret_cast<f32x4*>(p));
}

// ---------------- prep: bf16 weights (+transposes) and fused M ----------------
__global__ void prep_w(const float* __restrict__ kW1, const float* __restrict__ kW2,
                       const float* __restrict__ vW1, const float* __restrict__ vW2,
                       const float* __restrict__ A,  const float* __restrict__ Lp,
                       const float* __restrict__ sW1, const float* __restrict__ tW1,
                       const float* __restrict__ sW2, const float* __restrict__ tW2,
                       u16* __restrict__ wsb) {
  const int n = blockIdx.x * 256 + threadIdx.x;   // grid = 65536 threads exactly
  {
    u16 v = (u16)f2bf(kW2[n]);
    wsb[oKW2 + n] = v;
    wsb[oKW2T + (size_t)(n & 255) * 256 + (n >> 8)] = v;
    u16 w = (u16)f2bf(vW2[n]);
    wsb[oVW2 + n] = w;
    wsb[oVW2T + (size_t)(n & 255) * 256 + (n >> 8)] = w;
  }
  if (n < 24576) {
    wsb[oSW1 + n] = (u16)f2bf(sW1[n]);
    wsb[oTW1 + n] = (u16)f2bf(tW1[n]);
    wsb[oSW2 + n] = (u16)f2bf(sW2[n]);
    wsb[oTW2 + n] = (u16)f2bf(tW2[n]);
  }
  if (n < 16384) {
    u16 v = (u16)f2bf(kW1[n]);
    wsb[oKW1 + n] = v;
    wsb[oKW1T + (size_t)(n & 63) * 256 + (n >> 6)] = v;
  }
  if (n < 8192) {
    u16 v = (u16)f2bf(vW1[n]);
    wsb[oVW1 + n] = v;
    wsb[oVW1T + (size_t)(n & 31) * 256 + (n >> 5)] = v;
  }
  if (n < 4096) {  // M = (A - A^T) - L L^T
    int d = n >> 6, e = n & 63;
    int kmax = min(d, e);
    float sum = 0.f;
    for (int k = 0; k <= kmax; ++k) {
      float ld = (k < d) ? Lp[d * kDim + k] : log1pf(expf(Lp[d * kDim + d]));
      float le = (k < e) ? Lp[e * kDim + k] : log1pf(expf(Lp[e * kDim + e]));
      sum += ld * le;
    }
    wsb[oMb + n] = (u16)f2bf(A[d * kDim + e] - A[e * kDim + d] - sum);
  }
}

// ---------------- flow (fwd/inv) via MFMA ----------------
// 512 threads = 8 waves, 32 samples/block. fp32 x-state in LDS; bf16 operands.
template <bool FWD>
__global__ __launch_bounds__(512, 2)
void flow_mfma(const float* __restrict__ io_in, float* __restrict__ io_out,
               const u16* __restrict__ wsb,
               const float* __restrict__ b1s, const float* __restrict__ b2s,
               const float* __restrict__ b1t, const float* __restrict__ b2t) {
  __shared__ __align__(16) float Xs[32][68];     // fp32 state
  __shared__ __align__(16) u16   CondB[32][40];  // bf16 cond half
  __shared__ __align__(16) u16   H1[32][264];    // relu hidden, cols 0-127 s, 128-255 t
  __shared__ __align__(16) float Sv[32][36];
  __shared__ __align__(16) float Tv[32][36];

  const u16* W1s = wsb + oSW1;  // [6][128][32]
  const u16* W1t = wsb + oTW1;
  const u16* W2s = wsb + oSW2;  // [6][32][128]
  const u16* W2t = wsb + oTW2;

  const int tid  = threadIdx.x;
  const int lane = tid & 63, wv = tid >> 6;
  const int r = lane & 15, kg = lane >> 4;
  const size_t base = (size_t)blockIdx.x * 32;
  const int sm = tid >> 4, quad = tid & 15;       // io mapping: 1 float4/thread

  {
    f32x4 v = ntld4(io_in + (base + sm) * kDim + quad * 4);
    *reinterpret_cast<f32x4*>(&Xs[sm][quad * 4]) = v;
  }
  __syncthreads();

#pragma unroll 1
  for (int li = 0; li < kNl; ++li) {
    const int l = FWD ? li : (kNl - 1 - li);
    const int par = l & 1;
    const int cb = par ? kQd : 0;   // cond base col
    const int tb = par ? 0 : kQd;   // transform base col

    { // build bf16 cond
      int idx = tid * 2, s = idx >> 5, c = idx & 31;
      *reinterpret_cast<uint32_t*>(&CondB[s][c]) = pkbf(Xs[s][cb + c], Xs[s][cb + c + 1]);
    }
    __syncthreads();

    { // GEMM1: [32x32] @ W1^T -> relu -> H1 (s-net waves 0-3, t-net waves 4-7)
      const int net = wv >> 2;
      const int nc0 = (wv & 3) * 32;
      const u16* W1 = net ? W1t : W1s;
      const float* b1 = net ? b1t : b1s;
      uint4 b0 = *reinterpret_cast<const uint4*>(W1 + ((size_t)l*128 + nc0 + r) * 32 + kg*8);
      uint4 b1v = *reinterpret_cast<const uint4*>(W1 + ((size_t)l*128 + nc0 + 16 + r) * 32 + kg*8);
      uint4 a0 = *reinterpret_cast<const uint4*>(&CondB[r][kg*8]);
      uint4 a1 = *reinterpret_cast<const uint4*>(&CondB[16 + r][kg*8]);
      f32x4 acc[2][2] = {};
      acc[0][0] = mfma16(a0,b0,acc[0][0]); acc[0][1] = mfma16(a0,b1v,acc[0][1]);
      acc[1][0] = mfma16(a1,b0,acc[1][0]); acc[1][1] = mfma16(a1,b1v,acc[1][1]);
      float bn0 = b1[l*128 + nc0 + r], bn1 = b1[l*128 + nc0 + 16 + r];
      const int colbase = net * 128 + nc0;
#pragma unroll
      for (int mt = 0; mt < 2; ++mt)
#pragma unroll
        for (int reg = 0; reg < 4; ++reg) {
          int row = mt*16 + kg*4 + reg;
          H1[row][colbase + r]      = (u16)f2bf(fmaxf(acc[mt][0][reg] + bn0, 0.f));
          H1[row][colbase + 16 + r] = (u16)f2bf(fmaxf(acc[mt][1][reg] + bn1, 0.f));
        }
    }
    __syncthreads();

    { // GEMM2: [32x128] @ W2^T -> Sv (tanh+b2s) / Tv (+b2t)
      const int net = wv >> 2, mt = (wv >> 1) & 1, nt2 = wv & 1;
      const u16* W2 = net ? W2t : W2s;
      f32x4 acc = {};
#pragma unroll
      for (int kc = 0; kc < 4; ++kc) {
        uint4 a = *reinterpret_cast<const uint4*>(&H1[mt*16 + r][net*128 + kc*32 + kg*8]);
        uint4 b = *reinterpret_cast<const uint4*>(W2 + ((size_t)l*32 + nt2*16 + r) * 128 + kc*32 + kg*8);
        acc = mfma16(a, b, acc);
      }
      if (net == 0) {
        float b2 = b2s[l*32 + nt2*16 + r];
#pragma unroll
        for (int reg = 0; reg < 4; ++reg)
          Sv[mt*16 + kg*4 + reg][nt2*16 + r] = tanhf(acc[reg] + b2);
      } else {
        float b2 = b2t[l*32 + nt2*16 + r];
#pragma unroll
        for (int reg = 0; reg < 4; ++reg)
          Tv[mt*16 + kg*4 + reg][nt2*16 + r] = acc[reg] + b2;
      }
    }
    __syncthreads();

    { // update transformed half
#pragma unroll
      for (int it = 0; it < 2; ++it) {
        int idx = tid + it * 512, s = idx >> 5, d = idx & 31;
        float sv = Sv[s][d], tv = Tv[s][d];
        float x = Xs[s][tb + d];
        Xs[s][tb + d] = FWD ? (x * __expf(sv) + tv) : ((x - tv) * __expf(-sv));
      }
    }
    __syncthreads();
  }

  {
    f32x4 v = *reinterpret_cast<const f32x4*>(&Xs[sm][quad * 4]);
    ntst4(io_out + (base + sm) * kDim + quad * 4, v);
  }
}

// ---------------- RK4 via MFMA ----------------
__device__ __forceinline__ void gemm256_2x2(const u16* __restrict__ Ab, int lda,
                                            const u16* __restrict__ Wb,
                                            int r, int kg, int n0, f32x4 acc[2][2]) {
#pragma unroll
  for (int kc = 0; kc < 8; ++kc) {
    uint4 b0 = *reinterpret_cast<const uint4*>(Wb + (size_t)(n0 + r) * 256 + kc*32 + kg*8);
    uint4 b1 = *reinterpret_cast<const uint4*>(Wb + (size_t)(n0 + 16 + r) * 256 + kc*32 + kg*8);
    uint4 a0 = *reinterpret_cast<const uint4*>(Ab + (size_t)r * lda + kc*32 + kg*8);
    uint4 a1 = *reinterpret_cast<const uint4*>(Ab + (size_t)(16 + r) * lda + kc*32 + kg*8);
    acc[0][0] = mfma16(a0, b0, acc[0][0]); acc[0][1] = mfma16(a0, b1, acc[0][1]);
    acc[1][0] = mfma16(a1, b0, acc[1][0]); acc[1][1] = mfma16(a1, b1, acc[1][1]);
  }
}

__global__ __launch_bounds__(512, 2)
void rk4_mfma(float* __restrict__ qp, const float* __restrict__ u,
              const u16* __restrict__ wsb,
              const float* __restrict__ kb1, const float* __restrict__ kb2,
              const float* __restrict__ kW3,
              const float* __restrict__ vb1, const float* __restrict__ vb2,
              const float* __restrict__ vW3,
              const float* __restrict__ Bc) {
  __shared__ __align__(16) u16   Zs[32][72];
  __shared__ __align__(16) u16   B1[32][264];
  __shared__ __align__(16) u16   B2[32][264];
  __shared__ __align__(16) float gHs[32][68];
  float* dzf = reinterpret_cast<float*>(&B2[0][0]);  // f32 [32][68] overlay

  const u16* kW1b  = wsb + oKW1;
  const u16* kW1Tb = wsb + oKW1T;
  const u16* kW2b  = wsb + oKW2;
  const u16* kW2Tb = wsb + oKW2T;
  const u16* vW1b  = wsb + oVW1;
  const u16* vW1Tb = wsb + oVW1T;
  const u16* vW2b  = wsb + oVW2;
  const u16* vW2Tb = wsb + oVW2T;
  const u16* Mb    = wsb + oMb;

  const int tid  = threadIdx.x;
  const int lane = tid & 63, wv = tid >> 6;
  const int r = lane & 15, kg = lane >> 4;
  const int n0 = wv * 32;
  const size_t base = (size_t)blockIdx.x * 32;

  const int s  = tid >> 4;
  const int d0 = (tid & 15) * 4;
  float qp0[4], accRK[4] = {0.f, 0.f, 0.f, 0.f}, bc4[4];
  {
    f32x4 v = ntld4(qp + (base + s) * kDim + d0);
    qp0[0] = v.x; qp0[1] = v.y; qp0[2] = v.z; qp0[3] = v.w;
  }
  const float u_s = __builtin_nontemporal_load(u + base + s);
#pragma unroll
  for (int i = 0; i < 4; ++i)
    bc4[i] = (d0 + i >= kQd) ? Bc[d0 + i - kQd] : 0.0f;
  *reinterpret_cast<uint2*>(&Zs[s][d0]) =
      make_uint2(pkbf(qp0[0], qp0[1]), pkbf(qp0[2], qp0[3]));
  __syncthreads();

#pragma unroll 1
  for (int ev = 0; ev < 4; ++ev) {
    { // P1: h1 = softplus(Z @ kW1^T + kb1) -> B1
      f32x4 acc[2][2] = {};
#pragma unroll
      for (int kc = 0; kc < 2; ++kc) {
        uint4 b0 = *reinterpret_cast<const uint4*>(kW1b + (size_t)(n0 + r) * 64 + kc*32 + kg*8);
        uint4 b1 = *reinterpret_cast<const uint4*>(kW1b + (size_t)(n0 + 16 + r) * 64 + kc*32 + kg*8);
        uint4 a0 = *reinterpret_cast<const uint4*>(&Zs[r][kc*32 + kg*8]);
        uint4 a1 = *reinterpret_cast<const uint4*>(&Zs[16 + r][kc*32 + kg*8]);
        acc[0][0] = mfma16(a0,b0,acc[0][0]); acc[0][1] = mfma16(a0,b1,acc[0][1]);
        acc[1][0] = mfma16(a1,b0,acc[1][0]); acc[1][1] = mfma16(a1,b1,acc[1][1]);
      }
      float bn0 = kb1[n0 + r], bn1 = kb1[n0 + 16 + r];
#pragma unroll
      for (int mt = 0; mt < 2; ++mt)
#pragma unroll
        for (int reg = 0; reg < 4; ++reg) {
          int row = mt*16 + kg*4 + reg;
          B1[row][n0 + r]      = (u16)f2bf(__logf(1.f + __expf(acc[mt][0][reg] + bn0)));
          B1[row][n0 + 16 + r] = (u16)f2bf(__logf(1.f + __expf(acc[mt][1][reg] + bn1)));
        }
    }
    __syncthreads();

    { // P2: g2 = sigmoid(h1 @ kW2^T + kb2) * kW3 -> B2
      f32x4 acc[2][2] = {};
      gemm256_2x2(&B1[0][0], 264, kW2b, r, kg, n0, acc);
      float bn0 = kb2[n0 + r], bn1 = kb2[n0 + 16 + r];
      float w30 = kW3[n0 + r], w31 = kW3[n0 + 16 + r];
#pragma unroll
      for (int mt = 0; mt < 2; ++mt)
#pragma unroll
        for (int reg = 0; reg < 4; ++reg) {
          int row = mt*16 + kg*4 + reg;
          B2[row][n0 + r]      = (u16)f2bf(w30 / (1.f + __expf(-(acc[mt][0][reg] + bn0))));
          B2[row][n0 + 16 + r] = (u16)f2bf(w31 / (1.f + __expf(-(acc[mt][1][reg] + bn1))));
        }
    }
    __syncthreads();

    { // P3: gh1 = (g2 @ kW2) * s1, s1 = 1-exp(-h1)  -> B1 in place
      f32x4 acc[2][2] = {};
      gemm256_2x2(&B2[0][0], 264, kW2Tb, r, kg, n0, acc);
#pragma unroll
      for (int mt = 0; mt < 2; ++mt)
#pragma unroll
        for (int nt = 0; nt < 2; ++nt)
#pragma unroll
          for (int reg = 0; reg < 4; ++reg) {
            int row = mt*16 + kg*4 + reg, col = n0 + nt*16 + r;
            float h = bf2f(B1[row][col]);
            B1[row][col] = (u16)f2bf(acc[mt][nt][reg] * (1.f - __expf(-h)));
          }
    }
    __syncthreads();

    { // P4: gHs = gh1 @ kW1
      const int mt = wv >> 2, nt = wv & 3;
      f32x4 acc = {};
#pragma unroll
      for (int kc = 0; kc < 8; ++kc) {
        uint4 b = *reinterpret_cast<const uint4*>(kW1Tb + (size_t)(nt*16 + r) * 256 + kc*32 + kg*8);
        uint4 a = *reinterpret_cast<const uint4*>(&B1[mt*16 + r][kc*32 + kg*8]);
        acc = mfma16(a, b, acc);
      }
#pragma unroll
      for (int reg = 0; reg < 4; ++reg)
        gHs[mt*16 + kg*4 + reg][nt*16 + r] = acc[reg];
    }
    __syncthreads();

    { // P5: h1v = softplus(Zq @ vW1^T + vb1) -> B1   (K=32)
      f32x4 acc[2][2] = {};
      uint4 b0 = *reinterpret_cast<const uint4*>(vW1b + (size_t)(n0 + r) * 32 + kg*8);
      uint4 b1 = *reinterpret_cast<const uint4*>(vW1b + (size_t)(n0 + 16 + r) * 32 + kg*8);
      uint4 a0 = *reinterpret_cast<const uint4*>(&Zs[r][kg*8]);
      uint4 a1 = *reinterpret_cast<const uint4*>(&Zs[16 + r][kg*8]);
      acc[0][0] = mfma16(a0,b0,acc[0][0]); acc[0][1] = mfma16(a0,b1,acc[0][1]);
      acc[1][0] = mfma16(a1,b0,acc[1][0]); acc[1][1] = mfma16(a1,b1,acc[1][1]);
      float bn0 = vb1[n0 + r], bn1 = vb1[n0 + 16 + r];
#pragma unroll
      for (int mt = 0; mt < 2; ++mt)
#pragma unroll
        for (int reg = 0; reg < 4; ++reg) {
          int row = mt*16 + kg*4 + reg;
          B1[row][n0 + r]      = (u16)f2bf(__logf(1.f + __expf(acc[mt][0][reg] + bn0)));
          B1[row][n0 + 16 + r] = (u16)f2bf(__logf(1.f + __expf(acc[mt][1][reg] + bn1)));
        }
    }
    __syncthreads();

    { // P6: g2v = sigmoid(h1v @ vW2^T + vb2) * vW3 -> B2
      f32x4 acc[2][2] = {};
      gemm256_2x2(&B1[0][0], 264, vW2b, r, kg, n0, acc);
      float bn0 = vb2[n0 + r], bn1 = vb2[n0 + 16 + r];
      float w30 = vW3[n0 + r], w31 = vW3[n0 + 16 + r];
#pragma unroll
      for (int mt = 0; mt < 2; ++mt)
#pragma unroll
        for (int reg = 0; reg < 4; ++reg) {
          int row = mt*16 + kg*4 + reg;
          B2[row][n0 + r]      = (u16)f2bf(w30 / (1.f + __expf(-(acc[mt][0][reg] + bn0))));
          B2[row][n0 + 16 + r] = (u16)f2bf(w31 / (1.f + __expf(-(acc[mt][1][reg] + bn1))));
        }
    }
    __syncthreads();

    { // P7: gh1v = (g2v @ vW2) * s1v -> B1 in place
      f32x4 acc[2][2] = {};
      gemm256_2x2(&B2[0][0], 264, vW2Tb, r, kg, n0, acc);
#pragma unroll
      for (int mt = 0; mt < 2; ++mt)
#pragma unroll
        for (int nt = 0; nt < 2; ++nt)
#pragma unroll
          for (int reg = 0; reg < 4; ++reg) {
            int row = mt*16 + kg*4 + reg, col = n0 + nt*16 + r;
            float h = bf2f(B1[row][col]);
            B1[row][col] = (u16)f2bf(acc[mt][nt][reg] * (1.f - __expf(-h)));
          }
    }
    __syncthreads();

    if (wv < 4) { // P8: gHs[:, :32] += gh1v @ vW1
      const int mt = wv >> 1, nt = wv & 1;
      f32x4 acc = {};
#pragma unroll
      for (int kc = 0; kc < 8; ++kc) {
        uint4 b = *reinterpret_cast<const uint4*>(vW1Tb + (size_t)(nt*16 + r) * 256 + kc*32 + kg*8);
        uint4 a = *reinterpret_cast<const uint4*>(&B1[mt*16 + r][kc*32 + kg*8]);
        acc = mfma16(a, b, acc);
      }
#pragma unroll
      for (int reg = 0; reg < 4; ++reg)
        gHs[mt*16 + kg*4 + reg][nt*16 + r] += acc[reg];
    }
    __syncthreads();

    { // P9: dz = gH @ M^T -> dzf
      const int mt = wv >> 2, nt = wv & 3;
      f32x4 acc = {};
#pragma unroll
      for (int kc = 0; kc < 2; ++kc) {
        const float* gp = &gHs[mt*16 + r][kc*32 + kg*8];
        float4 ga = *reinterpret_cast<const float4*>(gp);
        float4 gb = *reinterpret_cast<const float4*>(gp + 4);
        uint4 a = make_uint4(pkbf(ga.x, ga.y), pkbf(ga.z, ga.w),
                             pkbf(gb.x, gb.y), pkbf(gb.z, gb.w));
        uint4 b = *reinterpret_cast<const uint4*>(Mb + (size_t)(nt*16 + r) * 64 + kc*32 + kg*8);
        acc = mfma16(a, b, acc);
      }
#pragma unroll
      for (int reg = 0; reg < 4; ++reg)
        dzf[(size_t)(mt*16 + kg*4 + reg) * 68 + nt*16 + r] = acc[reg];
    }
    __syncthreads();

    { // RK update
      const float cstep = (ev == 2) ? kDt : (0.5f * kDt);
      const float wgt   = (ev == 0 || ev == 3) ? 1.0f : 2.0f;
      float4 dv = *reinterpret_cast<const float4*>(dzf + (size_t)s * 68 + d0);
      float vv[4] = {dv.x, dv.y, dv.z, dv.w};
      float zn[4];
#pragma unroll
      for (int i = 0; i < 4; ++i) {
        vv[i] += u_s * bc4[i];
        accRK[i] += wgt * vv[i];
        zn[i] = qp0[i] + cstep * vv[i];
      }
      if (ev < 3)
        *reinterpret_cast<uint2*>(&Zs[s][d0]) =
            make_uint2(pkbf(zn[0], zn[1]), pkbf(zn[2], zn[3]));
    }
    __syncthreads();
  }

  {
    f32x4 v;
#pragma unroll
    for (int i = 0; i < 4; ++i) v[i] = qp0[i] + (kDt / 6.0f) * accRK[i];
    ntst4(qp + (base + s) * kDim + d0, v);
  }
}

// ---------------- host ----------------
extern "C" void kernel_launch(void* const* d_in, const int* in_sizes, int n_in,
                              void* d_out, int out_size, void* d_ws, size_t ws_size,
                              hipStream_t stream) {
  const float* h    = (const float*)d_in[0];
  const float* u    = (const float*)d_in[1];
  const float* sW1  = (const float*)d_in[2];
  const float* sb1  = (const float*)d_in[3];
  const float* sW2  = (const float*)d_in[4];
  const float* sb2  = (const float*)d_in[5];
  const float* tW1  = (const float*)d_in[6];
  const float* tb1  = (const float*)d_in[7];
  const float* tW2  = (const float*)d_in[8];
  const float* tb2  = (const float*)d_in[9];
  const float* kW1  = (const float*)d_in[10];
  const float* kb1  = (const float*)d_in[11];
  const float* kW2  = (const float*)d_in[12];
  const float* kb2  = (const float*)d_in[13];
  const float* kW3  = (const float*)d_in[14];
  const float* vW1  = (const float*)d_in[16];
  const float* vb1  = (const float*)d_in[17];
  const float* vW2  = (const float*)d_in[18];
  const float* vb2  = (const float*)d_in[19];
  const float* vW3  = (const float*)d_in[20];
  const float* A    = (const float*)d_in[22];
  const float* Lp   = (const float*)d_in[23];
  const float* Bc   = (const float*)d_in[24];
  (void)n_in; (void)ws_size; (void)out_size;

  float* out = (float*)d_out;
  u16*   wsb = (u16*)d_ws;

  const int B = in_sizes[0] / kDim;        // 131072
  const int grid32 = B / 32;               // 4096

  prep_w<<<256, 256, 0, stream>>>(kW1, kW2, vW1, vW2, A, Lp, sW1, tW1, sW2, tW2, wsb);
  flow_mfma<true><<<grid32, 512, 0, stream>>>(h, out, wsb, sb1, sb2, tb1, tb2);
  rk4_mfma<<<grid32, 512, 0, stream>>>(out, u, wsb, kb1, kb2, kW3,
                                       vb1, vb2, vW3, Bc);
  flow_mfma<false><<<grid32, 512, 0, stream>>>(out, out, wsb, sb1, sb2, tb1, tb2);
}

// Round 5
// 1575.279 us; speedup vs baseline: 9.5598x; 1.3341x over previous
//
#include <hip/hip_runtime.h>
#include <cstdint>
#include <cstddef>

// ---------------------------------------------------------------------------
// HamiltonianFlowModel: flow_fwd -> RK4(grad_H @ M^T) -> flow_inv
// R5: bound in-flight operand loads (#pragma unroll 2 on K-loops) to kill
//     the remaining VGPR spills at the 128-reg cap.
// ---------------------------------------------------------------------------

namespace {
constexpr int kDim = 64;   // DIM
constexpr int kQd  = 32;   // DIM/2
constexpr int kNl  = 6;    // NLAYERS
constexpr float kDt = 0.05f;

// ws layout (u16 element offsets)
constexpr size_t oKW1  = 0;        // [256][64]
constexpr size_t oKW1T = 16384;    // [64][256]
constexpr size_t oKW2  = 32768;    // [256][256]
constexpr size_t oKW2T = 98304;    // [256][256]
constexpr size_t oVW1  = 163840;   // [256][32]
constexpr size_t oVW1T = 172032;   // [32][256]
constexpr size_t oVW2  = 180224;   // [256][256]
constexpr size_t oVW2T = 245760;   // [256][256]
constexpr size_t oMb   = 311296;   // [64][64]
constexpr size_t oSW1  = 315392;   // [6][128][32]
constexpr size_t oTW1  = 339968;   // [6][128][32]
constexpr size_t oSW2  = 364544;   // [6][32][128]
constexpr size_t oTW2  = 389120;   // [6][32][128]
}

typedef unsigned short u16;
typedef float  f32x4 __attribute__((ext_vector_type(4)));
typedef __bf16 b16x8 __attribute__((ext_vector_type(8)));

// ---------------- helpers ----------------
__device__ __forceinline__ uint32_t f2bf(float f) {
  uint32_t u = __float_as_uint(f);
  return (u + 0x7fffu + ((u >> 16) & 1u)) >> 16;   // RNE bf16
}
__device__ __forceinline__ uint32_t pkbf(float a, float b) {
  return f2bf(a) | (f2bf(b) << 16);
}
__device__ __forceinline__ float bf2f(u16 v) {
  return __uint_as_float(((uint32_t)v) << 16);
}
__device__ __forceinline__ f32x4 mfma16(uint4 a, uint4 b, f32x4 c) {
  return __builtin_amdgcn_mfma_f32_16x16x32_bf16(
      __builtin_bit_cast(b16x8, a), __builtin_bit_cast(b16x8, b), c, 0, 0, 0);
}
__device__ __forceinline__ f32x4 ntld4(const float* p) {
  return __builtin_nontemporal_load(reinterpret_cast<const f32x4*>(p));
}
__device__ __forceinline__ void ntst4(float* p, f32x4 v) {
  __builtin_nontemporal_store(v, reinterpret_cast<f32x4*>(p));
}

// ---------------- prep: bf16 weights (+transposes) and fused M ----------------
__global__ void prep_w(const float* __restrict__ kW1, const float* __restrict__ kW2,
                       const float* __restrict__ vW1, const float* __restrict__ vW2,
                       const float* __restrict__ A,  const float* __restrict__ Lp,
                       const float* __restrict__ sW1, const float* __restrict__ tW1,
                       const float* __restrict__ sW2, const float* __restrict__ tW2,
                       u16* __restrict__ wsb) {
  const int n = blockIdx.x * 256 + threadIdx.x;   // grid = 65536 threads exactly
  {
    u16 v = (u16)f2bf(kW2[n]);
    wsb[oKW2 + n] = v;
    wsb[oKW2T + (size_t)(n & 255) * 256 + (n >> 8)] = v;
    u16 w = (u16)f2bf(vW2[n]);
    wsb[oVW2 + n] = w;
    wsb[oVW2T + (size_t)(n & 255) * 256 + (n >> 8)] = w;
  }
  if (n < 24576) {
    wsb[oSW1 + n] = (u16)f2bf(sW1[n]);
    wsb[oTW1 + n] = (u16)f2bf(tW1[n]);
    wsb[oSW2 + n] = (u16)f2bf(sW2[n]);
    wsb[oTW2 + n] = (u16)f2bf(tW2[n]);
  }
  if (n < 16384) {
    u16 v = (u16)f2bf(kW1[n]);
    wsb[oKW1 + n] = v;
    wsb[oKW1T + (size_t)(n & 63) * 256 + (n >> 6)] = v;
  }
  if (n < 8192) {
    u16 v = (u16)f2bf(vW1[n]);
    wsb[oVW1 + n] = v;
    wsb[oVW1T + (size_t)(n & 31) * 256 + (n >> 5)] = v;
  }
  if (n < 4096) {  // M = (A - A^T) - L L^T
    int d = n >> 6, e = n & 63;
    int kmax = min(d, e);
    float sum = 0.f;
    for (int k = 0; k <= kmax; ++k) {
      float ld = (k < d) ? Lp[d * kDim + k] : log1pf(expf(Lp[d * kDim + d]));
      float le = (k < e) ? Lp[e * kDim + k] : log1pf(expf(Lp[e * kDim + e]));
      sum += ld * le;
    }
    wsb[oMb + n] = (u16)f2bf(A[d * kDim + e] - A[e * kDim + d] - sum);
  }
}

// ---------------- flow (fwd/inv) via MFMA ----------------
// 512 threads = 8 waves, 32 samples/block. fp32 x-state in LDS; bf16 operands.
template <bool FWD>
__global__ __launch_bounds__(512, 2)
void flow_mfma(const float* __restrict__ io_in, float* __restrict__ io_out,
               const u16* __restrict__ wsb,
               const float* __restrict__ b1s, const float* __restrict__ b2s,
               const float* __restrict__ b1t, const float* __restrict__ b2t) {
  __shared__ __align__(16) float Xs[32][68];     // fp32 state
  __shared__ __align__(16) u16   CondB[32][40];  // bf16 cond half
  __shared__ __align__(16) u16   H1[32][264];    // relu hidden, cols 0-127 s, 128-255 t
  __shared__ __align__(16) float Sv[32][36];
  __shared__ __align__(16) float Tv[32][36];

  const u16* W1s = wsb + oSW1;  // [6][128][32]
  const u16* W1t = wsb + oTW1;
  const u16* W2s = wsb + oSW2;  // [6][32][128]
  const u16* W2t = wsb + oTW2;

  const int tid  = threadIdx.x;
  const int lane = tid & 63, wv = tid >> 6;
  const int r = lane & 15, kg = lane >> 4;
  const size_t base = (size_t)blockIdx.x * 32;
  const int sm = tid >> 4, quad = tid & 15;       // io mapping: 1 float4/thread

  {
    f32x4 v = ntld4(io_in + (base + sm) * kDim + quad * 4);
    *reinterpret_cast<f32x4*>(&Xs[sm][quad * 4]) = v;
  }
  __syncthreads();

#pragma unroll 1
  for (int li = 0; li < kNl; ++li) {
    const int l = FWD ? li : (kNl - 1 - li);
    const int par = l & 1;
    const int cb = par ? kQd : 0;   // cond base col
    const int tb = par ? 0 : kQd;   // transform base col

    { // build bf16 cond
      int idx = tid * 2, s = idx >> 5, c = idx & 31;
      *reinterpret_cast<uint32_t*>(&CondB[s][c]) = pkbf(Xs[s][cb + c], Xs[s][cb + c + 1]);
    }
    __syncthreads();

    { // GEMM1: [32x32] @ W1^T -> relu -> H1 (s-net waves 0-3, t-net waves 4-7)
      const int net = wv >> 2;
      const int nc0 = (wv & 3) * 32;
      const u16* W1 = net ? W1t : W1s;
      const float* b1 = net ? b1t : b1s;
      uint4 b0 = *reinterpret_cast<const uint4*>(W1 + ((size_t)l*128 + nc0 + r) * 32 + kg*8);
      uint4 b1v = *reinterpret_cast<const uint4*>(W1 + ((size_t)l*128 + nc0 + 16 + r) * 32 + kg*8);
      uint4 a0 = *reinterpret_cast<const uint4*>(&CondB[r][kg*8]);
      uint4 a1 = *reinterpret_cast<const uint4*>(&CondB[16 + r][kg*8]);
      f32x4 acc[2][2] = {};
      acc[0][0] = mfma16(a0,b0,acc[0][0]); acc[0][1] = mfma16(a0,b1v,acc[0][1]);
      acc[1][0] = mfma16(a1,b0,acc[1][0]); acc[1][1] = mfma16(a1,b1v,acc[1][1]);
      float bn0 = b1[l*128 + nc0 + r], bn1 = b1[l*128 + nc0 + 16 + r];
      const int colbase = net * 128 + nc0;
#pragma unroll
      for (int mt = 0; mt < 2; ++mt)
#pragma unroll
        for (int reg = 0; reg < 4; ++reg) {
          int row = mt*16 + kg*4 + reg;
          H1[row][colbase + r]      = (u16)f2bf(fmaxf(acc[mt][0][reg] + bn0, 0.f));
          H1[row][colbase + 16 + r] = (u16)f2bf(fmaxf(acc[mt][1][reg] + bn1, 0.f));
        }
    }
    __syncthreads();

    { // GEMM2: [32x128] @ W2^T -> Sv (tanh+b2s) / Tv (+b2t)
      const int net = wv >> 2, mt = (wv >> 1) & 1, nt2 = wv & 1;
      const u16* W2 = net ? W2t : W2s;
      f32x4 acc = {};
#pragma unroll 2
      for (int kc = 0; kc < 4; ++kc) {
        uint4 a = *reinterpret_cast<const uint4*>(&H1[mt*16 + r][net*128 + kc*32 + kg*8]);
        uint4 b = *reinterpret_cast<const uint4*>(W2 + ((size_t)l*32 + nt2*16 + r) * 128 + kc*32 + kg*8);
        acc = mfma16(a, b, acc);
      }
      if (net == 0) {
        float b2 = b2s[l*32 + nt2*16 + r];
#pragma unroll
        for (int reg = 0; reg < 4; ++reg)
          Sv[mt*16 + kg*4 + reg][nt2*16 + r] = tanhf(acc[reg] + b2);
      } else {
        float b2 = b2t[l*32 + nt2*16 + r];
#pragma unroll
        for (int reg = 0; reg < 4; ++reg)
          Tv[mt*16 + kg*4 + reg][nt2*16 + r] = acc[reg] + b2;
      }
    }
    __syncthreads();

    { // update transformed half
#pragma unroll
      for (int it = 0; it < 2; ++it) {
        int idx = tid + it * 512, s = idx >> 5, d = idx & 31;
        float sv = Sv[s][d], tv = Tv[s][d];
        float x = Xs[s][tb + d];
        Xs[s][tb + d] = FWD ? (x * __expf(sv) + tv) : ((x - tv) * __expf(-sv));
      }
    }
    __syncthreads();
  }

  {
    f32x4 v = *reinterpret_cast<const f32x4*>(&Xs[sm][quad * 4]);
    ntst4(io_out + (base + sm) * kDim + quad * 4, v);
  }
}

// ---------------- RK4 via MFMA ----------------
// unroll 2: bound in-flight uint4 operand loads (~8-12) so live VGPRs < 128.
__device__ __forceinline__ void gemm256_2x2(const u16* __restrict__ Ab, int lda,
                                            const u16* __restrict__ Wb,
                                            int r, int kg, int n0, f32x4 acc[2][2]) {
#pragma unroll 2
  for (int kc = 0; kc < 8; ++kc) {
    uint4 b0 = *reinterpret_cast<const uint4*>(Wb + (size_t)(n0 + r) * 256 + kc*32 + kg*8);
    uint4 b1 = *reinterpret_cast<const uint4*>(Wb + (size_t)(n0 + 16 + r) * 256 + kc*32 + kg*8);
    uint4 a0 = *reinterpret_cast<const uint4*>(Ab + (size_t)r * lda + kc*32 + kg*8);
    uint4 a1 = *reinterpret_cast<const uint4*>(Ab + (size_t)(16 + r) * lda + kc*32 + kg*8);
    acc[0][0] = mfma16(a0, b0, acc[0][0]); acc[0][1] = mfma16(a0, b1, acc[0][1]);
    acc[1][0] = mfma16(a1, b0, acc[1][0]); acc[1][1] = mfma16(a1, b1, acc[1][1]);
  }
}

__global__ __launch_bounds__(512, 2)
void rk4_mfma(float* __restrict__ qp, const float* __restrict__ u,
              const u16* __restrict__ wsb,
              const float* __restrict__ kb1, const float* __restrict__ kb2,
              const float* __restrict__ kW3,
              const float* __restrict__ vb1, const float* __restrict__ vb2,
              const float* __restrict__ vW3,
              const float* __restrict__ Bc) {
  __shared__ __align__(16) u16   Zs[32][72];
  __shared__ __align__(16) u16   B1[32][264];
  __shared__ __align__(16) u16   B2[32][264];
  __shared__ __align__(16) float gHs[32][68];
  float* dzf = reinterpret_cast<float*>(&B2[0][0]);  // f32 [32][68] overlay

  const u16* kW1b  = wsb + oKW1;
  const u16* kW1Tb = wsb + oKW1T;
  const u16* kW2b  = wsb + oKW2;
  const u16* kW2Tb = wsb + oKW2T;
  const u16* vW1b  = wsb + oVW1;
  const u16* vW1Tb = wsb + oVW1T;
  const u16* vW2b  = wsb + oVW2;
  const u16* vW2Tb = wsb + oVW2T;
  const u16* Mb    = wsb + oMb;

  const int tid  = threadIdx.x;
  const int lane = tid & 63, wv = tid >> 6;
  const int r = lane & 15, kg = lane >> 4;
  const int n0 = wv * 32;
  const size_t base = (size_t)blockIdx.x * 32;

  const int s  = tid >> 4;
  const int d0 = (tid & 15) * 4;
  float qp0[4], accRK[4] = {0.f, 0.f, 0.f, 0.f}, bc4[4];
  {
    f32x4 v = ntld4(qp + (base + s) * kDim + d0);
    qp0[0] = v.x; qp0[1] = v.y; qp0[2] = v.z; qp0[3] = v.w;
  }
  const float u_s = __builtin_nontemporal_load(u + base + s);
#pragma unroll
  for (int i = 0; i < 4; ++i)
    bc4[i] = (d0 + i >= kQd) ? Bc[d0 + i - kQd] : 0.0f;
  *reinterpret_cast<uint2*>(&Zs[s][d0]) =
      make_uint2(pkbf(qp0[0], qp0[1]), pkbf(qp0[2], qp0[3]));
  __syncthreads();

#pragma unroll 1
  for (int ev = 0; ev < 4; ++ev) {
    { // P1: h1 = softplus(Z @ kW1^T + kb1) -> B1
      f32x4 acc[2][2] = {};
#pragma unroll
      for (int kc = 0; kc < 2; ++kc) {
        uint4 b0 = *reinterpret_cast<const uint4*>(kW1b + (size_t)(n0 + r) * 64 + kc*32 + kg*8);
        uint4 b1 = *reinterpret_cast<const uint4*>(kW1b + (size_t)(n0 + 16 + r) * 64 + kc*32 + kg*8);
        uint4 a0 = *reinterpret_cast<const uint4*>(&Zs[r][kc*32 + kg*8]);
        uint4 a1 = *reinterpret_cast<const uint4*>(&Zs[16 + r][kc*32 + kg*8]);
        acc[0][0] = mfma16(a0,b0,acc[0][0]); acc[0][1] = mfma16(a0,b1,acc[0][1]);
        acc[1][0] = mfma16(a1,b0,acc[1][0]); acc[1][1] = mfma16(a1,b1,acc[1][1]);
      }
      float bn0 = kb1[n0 + r], bn1 = kb1[n0 + 16 + r];
#pragma unroll
      for (int mt = 0; mt < 2; ++mt)
#pragma unroll
        for (int reg = 0; reg < 4; ++reg) {
          int row = mt*16 + kg*4 + reg;
          B1[row][n0 + r]      = (u16)f2bf(__logf(1.f + __expf(acc[mt][0][reg] + bn0)));
          B1[row][n0 + 16 + r] = (u16)f2bf(__logf(1.f + __expf(acc[mt][1][reg] + bn1)));
        }
    }
    __syncthreads();

    { // P2: g2 = sigmoid(h1 @ kW2^T + kb2) * kW3 -> B2
      f32x4 acc[2][2] = {};
      gemm256_2x2(&B1[0][0], 264, kW2b, r, kg, n0, acc);
      float bn0 = kb2[n0 + r], bn1 = kb2[n0 + 16 + r];
      float w30 = kW3[n0 + r], w31 = kW3[n0 + 16 + r];
#pragma unroll
      for (int mt = 0; mt < 2; ++mt)
#pragma unroll
        for (int reg = 0; reg < 4; ++reg) {
          int row = mt*16 + kg*4 + reg;
          B2[row][n0 + r]      = (u16)f2bf(w30 / (1.f + __expf(-(acc[mt][0][reg] + bn0))));
          B2[row][n0 + 16 + r] = (u16)f2bf(w31 / (1.f + __expf(-(acc[mt][1][reg] + bn1))));
        }
    }
    __syncthreads();

    { // P3: gh1 = (g2 @ kW2) * s1, s1 = 1-exp(-h1)  -> B1 in place
      f32x4 acc[2][2] = {};
      gemm256_2x2(&B2[0][0], 264, kW2Tb, r, kg, n0, acc);
#pragma unroll
      for (int mt = 0; mt < 2; ++mt)
#pragma unroll
        for (int nt = 0; nt < 2; ++nt)
#pragma unroll
          for (int reg = 0; reg < 4; ++reg) {
            int row = mt*16 + kg*4 + reg, col = n0 + nt*16 + r;
            float h = bf2f(B1[row][col]);
            B1[row][col] = (u16)f2bf(acc[mt][nt][reg] * (1.f - __expf(-h)));
          }
    }
    __syncthreads();

    { // P4: gHs = gh1 @ kW1
      const int mt = wv >> 2, nt = wv & 3;
      f32x4 acc = {};
#pragma unroll 2
      for (int kc = 0; kc < 8; ++kc) {
        uint4 b = *reinterpret_cast<const uint4*>(kW1Tb + (size_t)(nt*16 + r) * 256 + kc*32 + kg*8);
        uint4 a = *reinterpret_cast<const uint4*>(&B1[mt*16 + r][kc*32 + kg*8]);
        acc = mfma16(a, b, acc);
      }
#pragma unroll
      for (int reg = 0; reg < 4; ++reg)
        gHs[mt*16 + kg*4 + reg][nt*16 + r] = acc[reg];
    }
    __syncthreads();

    { // P5: h1v = softplus(Zq @ vW1^T + vb1) -> B1   (K=32)
      f32x4 acc[2][2] = {};
      uint4 b0 = *reinterpret_cast<const uint4*>(vW1b + (size_t)(n0 + r) * 32 + kg*8);
      uint4 b1 = *reinterpret_cast<const uint4*>(vW1b + (size_t)(n0 + 16 + r) * 32 + kg*8);
      uint4 a0 = *reinterpret_cast<const uint4*>(&Zs[r][kg*8]);
      uint4 a1 = *reinterpret_cast<const uint4*>(&Zs[16 + r][kg*8]);
      acc[0][0] = mfma16(a0,b0,acc[0][0]); acc[0][1] = mfma16(a0,b1,acc[0][1]);
      acc[1][0] = mfma16(a1,b0,acc[1][0]); acc[1][1] = mfma16(a1,b1,acc[1][1]);
      float bn0 = vb1[n0 + r], bn1 = vb1[n0 + 16 + r];
#pragma unroll
      for (int mt = 0; mt < 2; ++mt)
#pragma unroll
        for (int reg = 0; reg < 4; ++reg) {
          int row = mt*16 + kg*4 + reg;
          B1[row][n0 + r]      = (u16)f2bf(__logf(1.f + __expf(acc[mt][0][reg] + bn0)));
          B1[row][n0 + 16 + r] = (u16)f2bf(__logf(1.f + __expf(acc[mt][1][reg] + bn1)));
        }
    }
    __syncthreads();

    { // P6: g2v = sigmoid(h1v @ vW2^T + vb2) * vW3 -> B2
      f32x4 acc[2][2] = {};
      gemm256_2x2(&B1[0][0], 264, vW2b, r, kg, n0, acc);
      float bn0 = vb2[n0 + r], bn1 = vb2[n0 + 16 + r];
      float w30 = vW3[n0 + r], w31 = vW3[n0 + 16 + r];
#pragma unroll
      for (int mt = 0; mt < 2; ++mt)
#pragma unroll
        for (int reg = 0; reg < 4; ++reg) {
          int row = mt*16 + kg*4 + reg;
          B2[row][n0 + r]      = (u16)f2bf(w30 / (1.f + __expf(-(acc[mt][0][reg] + bn0))));
          B2[row][n0 + 16 + r] = (u16)f2bf(w31 / (1.f + __expf(-(acc[mt][1][reg] + bn1))));
        }
    }
    __syncthreads();

    { // P7: gh1v = (g2v @ vW2) * s1v -> B1 in place
      f32x4 acc[2][2] = {};
      gemm256_2x2(&B2[0][0], 264, vW2Tb, r, kg, n0, acc);
#pragma unroll
      for (int mt = 0; mt < 2; ++mt)
#pragma unroll
        for (int nt = 0; nt < 2; ++nt)
#pragma unroll
          for (int reg = 0; reg < 4; ++reg) {
            int row = mt*16 + kg*4 + reg, col = n0 + nt*16 + r;
            float h = bf2f(B1[row][col]);
            B1[row][col] = (u16)f2bf(acc[mt][nt][reg] * (1.f - __expf(-h)));
          }
    }
    __syncthreads();

    if (wv < 4) { // P8: gHs[:, :32] += gh1v @ vW1
      const int mt = wv >> 1, nt = wv & 1;
      f32x4 acc = {};
#pragma unroll 2
      for (int kc = 0; kc < 8; ++kc) {
        uint4 b = *reinterpret_cast<const uint4*>(vW1Tb + (size_t)(nt*16 + r) * 256 + kc*32 + kg*8);
        uint4 a = *reinterpret_cast<const uint4*>(&B1[mt*16 + r][kc*32 + kg*8]);
        acc = mfma16(a, b, acc);
      }
#pragma unroll
      for (int reg = 0; reg < 4; ++reg)
        gHs[mt*16 + kg*4 + reg][nt*16 + r] += acc[reg];
    }
    __syncthreads();

    { // P9: dz = gH @ M^T -> dzf
      const int mt = wv >> 2, nt = wv & 3;
      f32x4 acc = {};
#pragma unroll
      for (int kc = 0; kc < 2; ++kc) {
        const float* gp = &gHs[mt*16 + r][kc*32 + kg*8];
        float4 ga = *reinterpret_cast<const float4*>(gp);
        float4 gb = *reinterpret_cast<const float4*>(gp + 4);
        uint4 a = make_uint4(pkbf(ga.x, ga.y), pkbf(ga.z, ga.w),
                             pkbf(gb.x, gb.y), pkbf(gb.z, gb.w));
        uint4 b = *reinterpret_cast<const uint4*>(Mb + (size_t)(nt*16 + r) * 64 + kc*32 + kg*8);
        acc = mfma16(a, b, acc);
      }
#pragma unroll
      for (int reg = 0; reg < 4; ++reg)
        dzf[(size_t)(mt*16 + kg*4 + reg) * 68 + nt*16 + r] = acc[reg];
    }
    __syncthreads();

    { // RK update
      const float cstep = (ev == 2) ? kDt : (0.5f * kDt);
      const float wgt   = (ev == 0 || ev == 3) ? 1.0f : 2.0f;
      float4 dv = *reinterpret_cast<const float4*>(dzf + (size_t)s * 68 + d0);
      float vv[4] = {dv.x, dv.y, dv.z, dv.w};
      float zn[4];
#pragma unroll
      for (int i = 0; i < 4; ++i) {
        vv[i] += u_s * bc4[i];
        accRK[i] += wgt * vv[i];
        zn[i] = qp0[i] + cstep * vv[i];
      }
      if (ev < 3)
        *reinterpret_cast<uint2*>(&Zs[s][d0]) =
            make_uint2(pkbf(zn[0], zn[1]), pkbf(zn[2], zn[3]));
    }
    __syncthreads();
  }

  {
    f32x4 v;
#pragma unroll
    for (int i = 0; i < 4; ++i) v[i] = qp0[i] + (kDt / 6.0f) * accRK[i];
    ntst4(qp + (base + s) * kDim + d0, v);
  }
}

// ---------------- host ----------------
extern "C" void kernel_launch(void* const* d_in, const int* in_sizes, int n_in,
                              void* d_out, int out_size, void* d_ws, size_t ws_size,
                              hipStream_t stream) {
  const float* h    = (const float*)d_in[0];
  const float* u    = (const float*)d_in[1];
  const float* sW1  = (const float*)d_in[2];
  const float* sb1  = (const float*)d_in[3];
  const float* sW2  = (const float*)d_in[4];
  const float* sb2  = (const float*)d_in[5];
  const float* tW1  = (const float*)d_in[6];
  const float* tb1  = (const float*)d_in[7];
  const float* tW2  = (const float*)d_in[8];
  const float* tb2  = (const float*)d_in[9];
  const float* kW1  = (const float*)d_in[10];
  const float* kb1  = (const float*)d_in[11];
  const float* kW2  = (const float*)d_in[12];
  const float* kb2  = (const float*)d_in[13];
  const float* kW3  = (const float*)d_in[14];
  const float* vW1  = (const float*)d_in[16];
  const float* vb1  = (const float*)d_in[17];
  const float* vW2  = (const float*)d_in[18];
  const float* vb2  = (const float*)d_in[19];
  const float* vW3  = (const float*)d_in[20];
  const float* A    = (const float*)d_in[22];
  const float* Lp   = (const float*)d_in[23];
  const float* Bc   = (const float*)d_in[24];
  (void)n_in; (void)ws_size; (void)out_size;

  float* out = (float*)d_out;
  u16*   wsb = (u16*)d_ws;

  const int B = in_sizes[0] / kDim;        // 131072
  const int grid32 = B / 32;               // 4096

  prep_w<<<256, 256, 0, stream>>>(kW1, kW2, vW1, vW2, A, Lp, sW1, tW1, sW2, tW2, wsb);
  flow_mfma<true><<<grid32, 512, 0, stream>>>(h, out, wsb, sb1, sb2, tb1, tb2);
  rk4_mfma<<<grid32, 512, 0, stream>>>(out, u, wsb, kb1, kb2, kW3,
                                       vb1, vb2, vW3, Bc);
  flow_mfma<false><<<grid32, 512, 0, stream>>>(out, out, wsb, sb1, sb2, tb1, tb2);
}